// Round 18
// baseline (749.255 us; speedup 1.0000x reference)
//
#include <hip/hip_runtime.h>

#define N_NODES 20000
#define N_EDGES 320000
#define DIN     256
#define DMODEL  512
#define TD      1536   // 3*D
#define FFD     2048
#define DOUT    128

typedef _Float16 f16;
typedef f16 f16x8 __attribute__((ext_vector_type(8)));
typedef f16 f16x4 __attribute__((ext_vector_type(4)));
typedef f16 f16x2 __attribute__((ext_vector_type(2)));
typedef float f32x4 __attribute__((ext_vector_type(4)));

__device__ __forceinline__ void cstore(float* p, float v) { *p = v; }
__device__ __forceinline__ void cstore(f16* p, float v)   { *p = (f16)v; }

#if defined(__has_builtin)
#if __has_builtin(__builtin_amdgcn_global_load_lds)
#define USE_GLOAD_LDS 1
#endif
#endif

// ---------------------------------------------------------------------------
// fp16 MFMA GEMM v7: 128x128 tile, BK=32, 4 waves, mfma_f32_16x16x32_f16.
// r15 profile: LDS-BW-bound (48KB/iter through LDS vs 77cyc MFMA). Fix:
//  - B fragments read DIRECT from global (L2-resident weights) into VGPRs,
//    prefetched 1 K-tile ahead (bcur/bnext). No B staging, no B LDS reads.
//  - A-only LDS: 4 x 8KB buffers, single barrier/iter (v6 proof: stage(kt)
//    writes buf last read at kt-2; reads(kt-2) < barrier(kt-1) < stage(kt)).
//  - total LDS 32KB (A bufs + epilogue repack overlap) -> 5 blocks/CU.
// FIFO vmcnt (issue order per iter: B(kt+1)[4] then stageA(kt+2)[2]):
//   steady queue = [A(kt)2,B(kt)4,A(kt+1)2,B(kt+1)4,A(kt+2)2] -> vmcnt(8)
//   drains A(kt)+B(kt); tails vmcnt(6), vmcnt(0).
// 1D grid + bijective XCD swizzle (n fastest -> A-panel L2 reuse).
// A rows read unguarded to the 128-aligned tile edge (allocated slack).
// K%32==0 (K>=96), N%128==0, M guarded at C-write and addmat-read.
// ---------------------------------------------------------------------------
template<typename TC, int HAS_BIAS, int HAS_ADD, int DO_RELU>
__global__ __launch_bounds__(256)
void gemm_mfma(const f16* __restrict__ A, const f16* __restrict__ Bt,
               const float* __restrict__ bias, const float* __restrict__ addmat,
               TC* __restrict__ C, int M, int N, int K)
{
    __shared__ f16 smem[16384];   // 32KB: 4 A-bufs (K-loop) / 128x128 repack (epi)
    const int tid  = threadIdx.x;
    const int lane = tid & 63;
    const int wid  = tid >> 6;
    const int wm = wid >> 1, wn = wid & 1;

    // bijective XCD swizzle (XCD ~ bid%8): contiguous wgid chunk per XCD,
    // n fastest => A-panel sharers co-located on one XCD's L2.
    const int nwg  = gridDim.x;
    const int bid  = blockIdx.x;
    const int q    = nwg >> 3, rres = nwg & 7;
    const int xcd  = bid & 7,  slot = bid >> 3;
    const int wgid = (xcd < rres ? xcd * (q + 1)
                                 : rres * (q + 1) + (xcd - rres) * q) + slot;
    const int ntn  = N >> 7;
    const int m0 = (wgid / ntn) * 128, n0 = (wgid % ntn) * 128;

    f32x4 acc[4][4];
    #pragma unroll
    for (int i = 0; i < 4; ++i)
        #pragma unroll
        for (int j = 0; j < 4; ++j)
            acc[i][j] = (f32x4)0.0f;

    const int r  = lane & 15;
    const int kg = lane >> 4;
    const int px = (kg ^ ((r >> 1) & 3)) << 3;

#ifdef USE_GLOAD_LDS
    const int seg0 = wid * 2, seg1 = wid * 2 + 1;       // 16 rows each
    const int row0 = seg0 * 16 + (lane >> 2);
    const int row1 = seg1 * 16 + (lane >> 2);
    const int kc0  = (lane & 3) ^ ((row0 >> 1) & 3);    // pre-swizzled chunk
    const int kc1  = (lane & 3) ^ ((row1 >> 1) & 3);
    const f16* a0 = A + (size_t)(m0 + row0) * K + kc0 * 8;
    const f16* a1 = A + (size_t)(m0 + row1) * K + kc1 * 8;
    // B direct-from-global per-lane base: frag n at +n*16*K, K-tile kt at +kt*32
    const f16* bq = Bt + (size_t)(n0 + wn * 64 + r) * K + kg * 8;

    auto stageA = [&](int buf, int k0) {
        f16* as = smem + buf * 4096;
        __builtin_amdgcn_global_load_lds(
            (const __attribute__((address_space(1))) void*)(a0 + k0),
            (__attribute__((address_space(3))) void*)&as[seg0 * 512], 16, 0, 0);
        __builtin_amdgcn_global_load_lds(
            (const __attribute__((address_space(1))) void*)(a1 + k0),
            (__attribute__((address_space(3))) void*)&as[seg1 * 512], 16, 0, 0);
    };

    const int NT = K >> 5;
    f16x8 bcur[4], bnext[4];
    stageA(0, 0);                                   // A(0): 2 loads
    #pragma unroll
    for (int n = 0; n < 4; ++n)                     // B(0): 4 loads
        bcur[n] = *(const f16x8*)(bq + (size_t)n * 16 * K);
    stageA(1, 32);                                  // A(1): 2 loads
    for (int kt = 0; kt < NT; ++kt) {
        if (kt + 1 < NT) {                          // B(kt+1): 4 loads
            #pragma unroll
            for (int n = 0; n < 4; ++n)
                bnext[n] = *(const f16x8*)(bq + (size_t)n * 16 * K + (kt + 1) * 32);
        }
        if (kt + 2 < NT) {
            stageA((kt + 2) & 3, (kt + 2) << 5);    // A(kt+2): 2 loads
            asm volatile("s_waitcnt vmcnt(8)" ::: "memory");  // A(kt)+B(kt) landed
        } else if (kt + 1 < NT) {
            asm volatile("s_waitcnt vmcnt(6)" ::: "memory");
        } else {
            asm volatile("s_waitcnt vmcnt(0)" ::: "memory");
        }
        __builtin_amdgcn_s_barrier();               // single barrier per iter
        __builtin_amdgcn_sched_barrier(0);
        const f16* as = smem + (kt & 3) * 4096;
        f16x8 af[4];
        #pragma unroll
        for (int m = 0; m < 4; ++m)
            af[m] = *(const f16x8*)(&as[(wm * 64 + m * 16 + r) * 32 + px]);
        #pragma unroll
        for (int m = 0; m < 4; ++m)
            #pragma unroll
            for (int n = 0; n < 4; ++n)
                acc[m][n] = __builtin_amdgcn_mfma_f32_16x16x32_f16(
                    af[m], bcur[n], acc[m][n], 0, 0, 0);
        if (kt + 1 < NT) {
            #pragma unroll
            for (int n = 0; n < 4; ++n) bcur[n] = bnext[n];
        }
    }
#else
    for (int k0 = 0; k0 < K; k0 += 32) {
        #pragma unroll
        for (int it = 0; it < 2; ++it) {
            const int c   = tid + it * 256;
            const int row = c >> 2, kc = c & 3;
            const int widx = row * 32 + ((kc ^ ((row >> 1) & 3)) << 3);
            f16x8 va = {0, 0, 0, 0, 0, 0, 0, 0};
            const int ga = m0 + row;
            if (ga < M) va = *(const f16x8*)(A + (size_t)ga * K + k0 + kc * 8);
            *(f16x8*)(&smem[widx]) = va;
        }
        __syncthreads();
        f16x8 af[4], bfr[4];
        #pragma unroll
        for (int m = 0; m < 4; ++m)
            af[m] = *(const f16x8*)(&smem[(wm * 64 + m * 16 + r) * 32 + px]);
        #pragma unroll
        for (int n = 0; n < 4; ++n)
            bfr[n] = *(const f16x8*)(Bt + (size_t)(n0 + wn * 64 + n * 16 + r) * K + k0 + kg * 8);
        #pragma unroll
        for (int m = 0; m < 4; ++m)
            #pragma unroll
            for (int n = 0; n < 4; ++n)
                acc[m][n] = __builtin_amdgcn_mfma_f32_16x16x32_f16(
                    af[m], bfr[n], acc[m][n], 0, 0, 0);
        __syncthreads();
    }
#endif

    const int rq = lane >> 4;
    if constexpr (sizeof(TC) == 2) {
        __syncthreads();   // all waves done reading A bufs before repack clobbers
        #pragma unroll
        for (int m = 0; m < 4; ++m) {
            #pragma unroll
            for (int rr = 0; rr < 4; ++rr) {
                const int rl = wm * 64 + m * 16 + rq * 4 + rr;
                #pragma unroll
                for (int n = 0; n < 4; ++n) {
                    const int cl = wn * 64 + n * 16 + (lane & 15);
                    float v = acc[m][n][rr];
                    if (HAS_BIAS) v += bias[n0 + cl];
                    if (HAS_ADD && (m0 + rl) < M) v += addmat[(size_t)(m0 + rl) * N + n0 + cl];
                    if (DO_RELU) v = fmaxf(v, 0.f);
                    smem[rl * 128 + cl] = (f16)v;
                }
            }
        }
        __syncthreads();
        #pragma unroll
        for (int i = 0; i < 8; ++i) {
            const int ch  = tid + i * 256;          // 0..2047
            const int row = ch >> 4;
            const int cc  = (ch & 15) << 3;
            if (m0 + row < M)
                *(f16x8*)((f16*)C + (size_t)(m0 + row) * N + n0 + cc) =
                    *(const f16x8*)(&smem[row * 128 + cc]);
        }
    } else {
        #pragma unroll
        for (int m = 0; m < 4; ++m) {
            #pragma unroll
            for (int rr = 0; rr < 4; ++rr) {
                const int row = m0 + wm * 64 + m * 16 + rq * 4 + rr;
                if (row >= M) continue;
                #pragma unroll
                for (int n = 0; n < 4; ++n) {
                    const int col = n0 + wn * 64 + n * 16 + (lane & 15);
                    float v = acc[m][n][rr];
                    if (HAS_BIAS) v += bias[col];
                    if (HAS_ADD)  v += addmat[(size_t)row * N + col];
                    if (DO_RELU)  v = fmaxf(v, 0.f);
                    cstore(&C[(size_t)row * N + col], v);
                }
            }
        }
    }
}

// ---------------------------------------------------------------------------
// Weight transpose+convert: W[K][N] f32 -> Wt[N][K] f16. 32x32 LDS tiles.
// ---------------------------------------------------------------------------
__global__ void wt_kernel(const float* __restrict__ W, f16* __restrict__ Wt, int K, int N)
{
    __shared__ float t[32][33];
    const int k0 = blockIdx.x * 32, n0 = blockIdx.y * 32;
    const int tx = threadIdx.x & 31, ty = threadIdx.x >> 5;
    #pragma unroll
    for (int i = ty; i < 32; i += 8) {
        const int k = k0 + i;
        if (k < K && n0 + tx < N) t[i][tx] = W[(size_t)k * N + n0 + tx];
    }
    __syncthreads();
    #pragma unroll
    for (int i = ty; i < 32; i += 8) {
        const int n = n0 + i;
        if (n < N && k0 + tx < K) Wt[(size_t)n * K + k0 + tx] = (f16)t[tx][i];
    }
}

// f32 -> f16 elementwise (n % 4 == 0)
__global__ void f2h_kernel(const float* __restrict__ in, f16* __restrict__ out, int n)
{
    const int i = (blockIdx.x * 256 + threadIdx.x) * 4;
    if (i < n) {
        const float4 v = *(const float4*)(in + i);
        out[i + 0] = (f16)v.x; out[i + 1] = (f16)v.y;
        out[i + 2] = (f16)v.z; out[i + 3] = (f16)v.w;
    }
}

// ---------------------------------------------------------------------------
// Fused conv + kv-sum + q materialization (unchanged).
// ---------------------------------------------------------------------------
#define KV_CHUNK 32
#define KV_BLOCKS (N_NODES / KV_CHUNK)   // 625
__global__ __launch_bounds__(256, 2)
void kv_fused_kernel(const f16* __restrict__ qkv, const float* __restrict__ cw,
                     f16* __restrict__ q_all, float* __restrict__ kvg,
                     float* __restrict__ kv_part)
{
    __shared__ f16 rows[5][TD];
    const int tid = threadIdx.x;
    const int n0 = blockIdx.x * KV_CHUNK;
    const int h = tid >> 1, d0 = (tid & 1) * 4;

    float wk[4][5], wv[8][5], wq[8][5];
    if (h >= 64) {
        const int cb = (h - 64) * 24;
        #pragma unroll
        for (int dd = 0; dd < 4; ++dd)
            #pragma unroll
            for (int t = 0; t < 5; ++t)
                wk[dd][t] = cw[(cb + 8 + d0 + dd) * 5 + t];
        #pragma unroll
        for (int e = 0; e < 8; ++e)
            #pragma unroll
            for (int t = 0; t < 5; ++t)
                wv[e][t] = cw[(cb + 16 + e) * 5 + t];
    }
    if (tid >= 64 && tid < 128) {
        const int cb = (tid - 64) * 24;
        #pragma unroll
        for (int d = 0; d < 8; ++d)
            #pragma unroll
            for (int t = 0; t < 5; ++t)
                wq[d][t] = cw[(cb + d) * 5 + t];
    }

    for (int r = n0 - 2; r <= n0 + 2; ++r) {
        const int slot = ((r % 5) + 5) % 5;
        if (tid < 192) {
            f16x8 v = {0, 0, 0, 0, 0, 0, 0, 0};
            if (r >= 0 && r < N_NODES)
                v = *(const f16x8*)(qkv + (size_t)r * TD + tid * 8);
            *(f16x8*)(&rows[slot][tid * 8]) = v;
        }
    }
    __syncthreads();

    float acc[36] = {};

    for (int i = 0; i < KV_CHUNK; ++i) {
        const int n = n0 + i;

        f16x8 pre = {0, 0, 0, 0, 0, 0, 0, 0};
        const bool doPre = (i < KV_CHUNK - 1) && (tid < 192);
        if (doPre && (n + 3) < N_NODES)
            pre = *(const f16x8*)(qkv + (size_t)(n + 3) * TD + tid * 8);

        const f16* wr[5] = { rows[(((n - 2) % 5) + 5) % 5],
                             rows[(((n - 1) % 5) + 5) % 5],
                             rows[n % 5],
                             rows[(n + 1) % 5],
                             rows[(n + 2) % 5] };

        float kv4[4], vv[8];
        if (h < 64) {
            const int cb = h * 24;
            const f16x4 kd = *(const f16x4*)(wr[2] + cb + 8 + d0);
            const f16x8 vd = *(const f16x8*)(wr[2] + cb + 16);
            #pragma unroll
            for (int dd = 0; dd < 4; ++dd) kv4[dd] = fmaxf((float)kd[dd], 0.f);
            #pragma unroll
            for (int e = 0; e < 8; ++e) vv[e] = (float)vd[e];
        } else {
            const int cb = (h - 64) * 24;
            f16x4 ka[5]; f16x8 va[5];
            #pragma unroll
            for (int t = 0; t < 5; ++t) {
                ka[t] = *(const f16x4*)(wr[t] + cb + 8 + d0);
                va[t] = *(const f16x8*)(wr[t] + cb + 16);
            }
            #pragma unroll
            for (int dd = 0; dd < 4; ++dd) {
                float s = 0.f;
                #pragma unroll
                for (int t = 0; t < 5; ++t) s = fmaf(wk[dd][t], (float)ka[t][dd], s);
                kv4[dd] = fmaxf(s, 0.f);
            }
            #pragma unroll
            for (int e = 0; e < 8; ++e) {
                float s = 0.f;
                #pragma unroll
                for (int t = 0; t < 5; ++t) s = fmaf(wv[e][t], (float)va[t][e], s);
                vv[e] = s;
            }
        }
        #pragma unroll
        for (int dd = 0; dd < 4; ++dd) {
            #pragma unroll
            for (int e = 0; e < 8; ++e)
                acc[dd * 9 + e] = fmaf(kv4[dd], vv[e], acc[dd * 9 + e]);
            acc[dd * 9 + 8] += kv4[dd];
        }

        if (tid < 128) {
            f16x8 qv;
            if (tid < 64) {
                qv = *(const f16x8*)(wr[2] + tid * 24);
                #pragma unroll
                for (int d = 0; d < 8; ++d)
                    qv[d] = qv[d] > (f16)0 ? qv[d] : (f16)0;
            } else {
                const int cb = (tid - 64) * 24;
                f16x8 qa[5];
                #pragma unroll
                for (int t = 0; t < 5; ++t) qa[t] = *(const f16x8*)(wr[t] + cb);
                #pragma unroll
                for (int d = 0; d < 8; ++d) {
                    float s = 0.f;
                    #pragma unroll
                    for (int t = 0; t < 5; ++t) s = fmaf(wq[d][t], (float)qa[t][d], s);
                    qv[d] = (f16)fmaxf(s, 0.f);
                }
            }
            *(f16x8*)(q_all + (size_t)n * 1024 + tid * 8) = qv;
        }

        __syncthreads();
        if (doPre)
            *(f16x8*)(&rows[(n + 3) % 5][tid * 8]) = pre;
        __syncthreads();
    }

    if (kv_part) {
        float* dst = kv_part + (size_t)blockIdx.x * 9216 + tid * 36;
        #pragma unroll
        for (int i = 0; i < 36; ++i) dst[i] = acc[i];
    } else {
        #pragma unroll
        for (int dd = 0; dd < 4; ++dd)
            #pragma unroll
            for (int e = 0; e < 9; ++e)
                atomicAdd(&kvg[h * 72 + (d0 + dd) * 9 + e], acc[dd * 9 + e]);
    }
}

// kvg[j] = sum_b kv_part[b][j], j in [0,9216). Grid: 36 x 256.
__global__ void kv_reduce_kernel(const float* __restrict__ kv_part,
                                 float* __restrict__ kvg)
{
    const int j = blockIdx.x * 256 + threadIdx.x;
    float s = 0.f;
    for (int b = 0; b < KV_BLOCKS; ++b)
        s += kv_part[(size_t)b * 9216 + j];
    kvg[j] = s;
}

// ---------------------------------------------------------------------------
// o[n, h*8+e] = (sum_d q*kv[h,d,e]) / (sum_d q*kv[h,d,8] + 1e-15)
// ---------------------------------------------------------------------------
__global__ __launch_bounds__(256)
void attn_o_kernel(const f16* __restrict__ q_all, const float* __restrict__ kvg,
                   f16* __restrict__ o)
{
    __shared__ float kvt[72][128];   // [d*9+e][h]
    const int tid = threadIdx.x;
    for (int i = tid; i < 9216; i += 256) {
        const int hh = i & 127, j = i >> 7;
        kvt[j][hh] = kvg[hh * 72 + j];
    }
    __syncthreads();
    const int h = tid & 127, sub = tid >> 7;
    for (int nb = blockIdx.x; nb < N_NODES / 2; nb += gridDim.x) {
        const int n = nb * 2 + sub;
        const f16x8 qv8 = *(const f16x8*)(q_all + (size_t)n * 1024 + h * 8);
        float q[8];
        #pragma unroll
        for (int d = 0; d < 8; ++d) q[d] = (float)qv8[d];
        float num[8], den = 0.f;
        #pragma unroll
        for (int e = 0; e < 8; ++e) {
            float s = 0.f;
            #pragma unroll
            for (int d = 0; d < 8; ++d) s = fmaf(q[d], kvt[d * 9 + e][h], s);
            num[e] = s;
        }
        #pragma unroll
        for (int d = 0; d < 8; ++d) den = fmaf(q[d], kvt[d * 9 + 8][h], den);
        const float rinv = 1.f / (den + 1e-15f);
        f16x8 ov;
        #pragma unroll
        for (int e = 0; e < 8; ++e) ov[e] = (f16)(num[e] * rinv);
        *(f16x8*)(o + (size_t)n * 1024 + h * 8) = ov;
    }
}

// ---------------------------------------------------------------------------
// out_h = f16(resid + LN(y)*g + b). resid f16. out_h may alias y.
// ---------------------------------------------------------------------------
__global__ void ln_res_kernel(const f16* __restrict__ y, const f16* __restrict__ resid,
                              const float* __restrict__ g, const float* __restrict__ b,
                              f16* __restrict__ out_h)
{
    const int row = blockIdx.x;
    const int tid = threadIdx.x;
    const f16* yr = y + (size_t)row * DMODEL;
    const float v0 = (float)yr[tid], v1 = (float)yr[tid + 256];
    __shared__ float red[4], red2[4];
    float s = v0 + v1;
    #pragma unroll
    for (int o = 32; o > 0; o >>= 1) s += __shfl_down(s, o);
    if ((tid & 63) == 0) red[tid >> 6] = s;
    __syncthreads();
    const float mean = (red[0] + red[1] + red[2] + red[3]) * (1.0f / DMODEL);
    const float d0 = v0 - mean, d1 = v1 - mean;
    float q = d0 * d0 + d1 * d1;
    #pragma unroll
    for (int o = 32; o > 0; o >>= 1) q += __shfl_down(q, o);
    if ((tid & 63) == 0) red2[tid >> 6] = q;
    __syncthreads();
    const float var = (red2[0] + red2[1] + red2[2] + red2[3]) * (1.0f / DMODEL);
    const float inv = rsqrtf(var + 1e-5f);
    const f16* rr = resid + (size_t)row * DMODEL;
    const float o0 = (float)rr[tid]       + d0 * inv * g[tid]       + b[tid];
    const float o1 = (float)rr[tid + 256] + d1 * inv * g[tid + 256] + b[tid + 256];
    f16* oh = out_h + (size_t)row * DMODEL;
    oh[tid] = (f16)o0;
    oh[tid + 256] = (f16)o1;
}

// ---------------------------------------------------------------------------
// Graph normalization + counting sort
// ---------------------------------------------------------------------------
__global__ void deg_init_kernel(float* __restrict__ deg)
{
    const int i = blockIdx.x * 256 + threadIdx.x;
    if (i < N_NODES) deg[i] = 1.0f;
}

__global__ void deg_acc_kernel(const int* __restrict__ eirow, const float* __restrict__ ea,
                               float* __restrict__ deg)
{
    const int e = blockIdx.x * 256 + threadIdx.x;
    if (e < N_EDGES) atomicAdd(&deg[eirow[e]], ea[e]);
}

__global__ void dis_kernel(const float* __restrict__ deg, float* __restrict__ dis)
{
    const int i = blockIdx.x * 256 + threadIdx.x;
    if (i < N_NODES) dis[i] = rsqrtf(deg[i]);
}

__global__ void count_kernel(const int* __restrict__ eirow, int* __restrict__ cnt)
{
    const int e = blockIdx.x * 256 + threadIdx.x;
    if (e < N_EDGES) atomicAdd(&cnt[eirow[e]], 1);
}

__global__ void scan_kernel(const int* __restrict__ cnt, int* __restrict__ rowstart,
                            int* __restrict__ cursor)
{
    __shared__ int ls[1024];
    const int tid = threadIdx.x;
    const int base = tid * 20;
    int local[20];
    int s = 0;
    #pragma unroll
    for (int i = 0; i < 20; ++i) {
        const int idx = base + i;
        const int v = (idx < N_NODES) ? cnt[idx] : 0;
        local[i] = s;
        s += v;
    }
    ls[tid] = s;
    __syncthreads();
    for (int off = 1; off < 1024; off <<= 1) {
        const int v = (tid >= off) ? ls[tid - off] : 0;
        __syncthreads();
        ls[tid] += v;
        __syncthreads();
    }
    const int excl = (tid == 0) ? 0 : ls[tid - 1];
    #pragma unroll
    for (int i = 0; i < 20; ++i) {
        const int idx = base + i;
        if (idx < N_NODES) {
            const int st = excl + local[i];
            rowstart[idx] = st;
            cursor[idx] = st;
        }
    }
    if (tid == 1023) rowstart[N_NODES] = ls[1023];
}

__global__ void scatter_kernel(const int* __restrict__ eirow, int* __restrict__ cursor,
                               int* __restrict__ sorted)
{
    const int e = blockIdx.x * 256 + threadIdx.x;
    if (e < N_EDGES) {
        const int r = eirow[e];
        const int p = atomicAdd(&cursor[r], 1);
        sorted[p] = e;
    }
}

// ---------------------------------------------------------------------------
// Aggregation v3 (unchanged): LDS metadata prefetch + 4-wave row gathers.
// ---------------------------------------------------------------------------
__global__ __launch_bounds__(256)
void agg_kernel(const f16* __restrict__ srcf_h, const int* __restrict__ eicol,
                const float* __restrict__ ea, const float* __restrict__ dis,
                const int* __restrict__ rowstart, const int* __restrict__ sorted,
                f16* __restrict__ agg)
{
    __shared__ int   cbuf[256];
    __shared__ float wbuf[256];
    __shared__ float part[4][512];
    const int i = blockIdx.x;
    const int tid = threadIdx.x;
    const int lane = tid & 63, wv = tid >> 6;
    const float di = dis[i];
    const int s = rowstart[i];
    const int deg = rowstart[i + 1] - s;

    float acc[8] = {};
    for (int base = 0; base < deg; base += 256) {
        const int m = min(256, deg - base);
        if (tid < m) {
            const int e = sorted[s + base + tid];
            const int c = eicol[e];
            cbuf[tid] = c;
            wbuf[tid] = di * ea[e] * dis[c];
        }
        __syncthreads();
        #pragma unroll 2
        for (int p = wv; p < m; p += 4) {
            const int c = cbuf[p];
            const float w = wbuf[p];
            const f16x8 v = *(const f16x8*)(srcf_h + (size_t)c * DMODEL + lane * 8);
            #pragma unroll
            for (int j = 0; j < 8; ++j) acc[j] = fmaf(w, (float)v[j], acc[j]);
        }
        __syncthreads();
    }
    #pragma unroll
    for (int j = 0; j < 8; ++j) part[wv][lane * 8 + j] = acc[j];
    __syncthreads();
    const float wself = di * di;
    const f16x2 vs = *(const f16x2*)(srcf_h + (size_t)i * DMODEL + tid * 2);
    float a0 = wself * (float)vs[0], a1 = wself * (float)vs[1];
    #pragma unroll
    for (int w = 0; w < 4; ++w) {
        a0 += part[w][tid * 2];
        a1 += part[w][tid * 2 + 1];
    }
    f16x2 o;
    o[0] = (f16)fmaxf(a0, 0.f);
    o[1] = (f16)fmaxf(a1, 0.f);
    *(f16x2*)(agg + (size_t)i * DMODEL + tid * 2) = o;
}

// ---------------------------------------------------------------------------
// Workspace layout (bytes) — unchanged from rounds 12-17.
// ---------------------------------------------------------------------------
static constexpr size_t OFF_HH    = 0;              // f16 20,480,000
static constexpr size_t OFF_FF    = 20480000ull;    // f16 20,480,000
static constexpr size_t OFF_QKV   = 40960000ull;    // f16 61,440,000
static constexpr size_t OFF_SRC2  = 40960000ull;    // f16 20,480,000 (alias)
static constexpr size_t OFF_FFH   = 61440000ull;    // f16 81,920,000 (alias)
static constexpr size_t OFF_AGG   = 61440000ull;    // f16 40,960,000 (alias)
static constexpr size_t OFF_XH    = 102400000ull;   // f16 10,240,000
static constexpr size_t OFF_ATTN  = 102400000ull;   // f16 40,960,000 (alias)
static constexpr size_t WT_IN     = 143360000ull;
static constexpr size_t WT_QKV    = 143622144ull;
static constexpr size_t WT_PROJ   = 145195008ull;
static constexpr size_t WT_W1     = 146243584ull;
static constexpr size_t WT_W2     = 148340736ull;
static constexpr size_t WT_OUT    = 150437888ull;
static constexpr size_t OFF_KV    = 150568960ull;
static constexpr size_t OFF_DEG   = 150605824ull;
static constexpr size_t OFF_DIS   = 150685824ull;
static constexpr size_t OFF_RS    = 150765824ull;
static constexpr size_t OFF_CUR   = 150845888ull;
static constexpr size_t OFF_CNT   = 150925888ull;
static constexpr size_t OFF_SORT  = 151005888ull;   // -> 152,285,888
static constexpr size_t OFF_KVP   = 152285888ull;   // -> 175,325,888
static constexpr size_t WS_NEED_KVP = 175325888ull;

extern "C" void kernel_launch(void* const* d_in, const int* in_sizes, int n_in,
                              void* d_out, int out_size, void* d_ws, size_t ws_size,
                              hipStream_t stream)
{
    const float* x      = (const float*)d_in[0];
    const int*   ei     = (const int*)d_in[1];
    const float* ea     = (const float*)d_in[2];
    const float* pe     = (const float*)d_in[4];
    const float* W_in   = (const float*)d_in[5];
    const float* b_in   = (const float*)d_in[6];
    const float* W_qkv  = (const float*)d_in[7];
    const float* conv_w = (const float*)d_in[8];
    const float* W_proj = (const float*)d_in[9];
    const float* b_proj = (const float*)d_in[10];
    const float* g1     = (const float*)d_in[11];
    const float* beta1  = (const float*)d_in[12];
    const float* W1     = (const float*)d_in[13];
    const float* bf1    = (const float*)d_in[14];
    const float* W2     = (const float*)d_in[15];
    const float* bf2    = (const float*)d_in[16];
    const float* g2     = (const float*)d_in[17];
    const float* beta2  = (const float*)d_in[18];
    const float* W_out  = (const float*)d_in[19];
    const float* b_out  = (const float*)d_in[20];

    char* ws = (char*)d_ws;
    f16*   h_h    = (f16*)(ws + OFF_HH);
    f16*   ff     = (f16*)(ws + OFF_FF);
    f16*   qkv    = (f16*)(ws + OFF_QKV);
    f16*   src2   = (f16*)(ws + OFF_SRC2);
    f16*   ffh    = (f16*)(ws + OFF_FFH);
    f16*   agg    = (f16*)(ws + OFF_AGG);
    f16*   x_h    = (f16*)(ws + OFF_XH);
    f16*   q_all  = (f16*)(ws + OFF_ATTN);
    f16*   wt_in   = (f16*)(ws + WT_IN);
    f16*   wt_qkv  = (f16*)(ws + WT_QKV);
    f16*   wt_proj = (f16*)(ws + WT_PROJ);
    f16*   wt_w1   = (f16*)(ws + WT_W1);
    f16*   wt_w2   = (f16*)(ws + WT_W2);
    f16*   wt_out  = (f16*)(ws + WT_OUT);
    float* kvg    = (float*)(ws + OFF_KV);
    float* deg    = (float*)(ws + OFF_DEG);
    float* dis    = (float*)(ws + OFF_DIS);
    int*   rs     = (int*)(ws + OFF_RS);
    int*   cur    = (int*)(ws + OFF_CUR);
    int*   cnt    = (int*)(ws + OFF_CNT);
    int*   sorted = (int*)(ws + OFF_SORT);
    float* outp   = (float*)d_out;

    const bool twoStage = (ws_size >= WS_NEED_KVP);
    float* kv_part = twoStage ? (float*)(ws + OFF_KVP) : nullptr;

    const int* eirow = ei;
    const int* eicol = ei + N_EDGES;

    if (!twoStage)
        hipMemsetAsync(kvg, 0, 9216 * sizeof(float), stream);
    hipMemsetAsync(cnt, 0, N_NODES * sizeof(int), stream);

    // 0. weight transpose+convert (f32 [K][N] -> f16 [N][K])
    wt_kernel<<<dim3(DIN / 32,   DMODEL / 32), 256, 0, stream>>>(W_in,   wt_in,   DIN,    DMODEL);
    wt_kernel<<<dim3(DMODEL / 32, TD / 32),    256, 0, stream>>>(W_qkv,  wt_qkv,  DMODEL, TD);
    wt_kernel<<<dim3(1024 / 32,  DMODEL / 32), 256, 0, stream>>>(W_proj, wt_proj, 1024,   DMODEL);
    wt_kernel<<<dim3(DMODEL / 32, FFD / 32),   256, 0, stream>>>(W1,     wt_w1,   DMODEL, FFD);
    wt_kernel<<<dim3(FFD / 32,   DMODEL / 32), 256, 0, stream>>>(W2,     wt_w2,   FFD,    DMODEL);
    wt_kernel<<<dim3(DMODEL / 32, DOUT / 32),  256, 0, stream>>>(W_out,  wt_out,  DMODEL, DOUT);
    // 0b. x -> f16
    f2h_kernel<<<(N_NODES * DIN) / 1024, 256, 0, stream>>>(x, x_h, N_NODES * DIN);

    const int MT = (N_NODES + 127) / 128;   // 157

    // 1. h_h = f16(x@W_in + b_in + pe)
    gemm_mfma<f16, 1, 1, 0><<<MT * (DMODEL / 128), 256, 0, stream>>>(
        x_h, wt_in, b_in, pe, h_h, N_NODES, DMODEL, DIN);
    // 2. qkv = h_h@W_qkv (f16)
    gemm_mfma<f16, 0, 0, 0><<<MT * (TD / 128), 256, 0, stream>>>(
        h_h, wt_qkv, nullptr, nullptr, qkv, N_NODES, TD, DMODEL);
    // 3. fused conv + kv partials + q materialization
    kv_fused_kernel<<<KV_BLOCKS, 256, 0, stream>>>(qkv, conv_w, q_all, kvg, kv_part);
    if (twoStage)
        kv_reduce_kernel<<<36, 256, 0, stream>>>(kv_part, kvg);
    // 4. attention readout (in-place over q_all)
    attn_o_kernel<<<2500, 256, 0, stream>>>(q_all, kvg, q_all);
    // 5. src2 = attn_o@W_proj + b_proj (f16)
    gemm_mfma<f16, 1, 0, 0><<<MT * (DMODEL / 128), 256, 0, stream>>>(
        q_all, wt_proj, b_proj, nullptr, src2, N_NODES, DMODEL, 1024);
    // 6. src2 = f16(h_h + LN(src2))  (in-place)
    ln_res_kernel<<<N_NODES, 256, 0, stream>>>(src2, h_h, g1, beta1, src2);
    // 7. ffh = relu(src2@W1 + bf1) (f16)
    gemm_mfma<f16, 1, 0, 1><<<MT * (FFD / 128), 256, 0, stream>>>(
        src2, wt_w1, bf1, nullptr, ffh, N_NODES, FFD, DMODEL);
    // 8. ff = ffh@W2 + bf2 (f16)
    gemm_mfma<f16, 1, 0, 0><<<MT * (DMODEL / 128), 256, 0, stream>>>(
        ffh, wt_w2, bf2, nullptr, ff, N_NODES, DMODEL, FFD);
    // 9. ff = f16(src2 + LN(ff))  (in-place; agg gather source)
    ln_res_kernel<<<N_NODES, 256, 0, stream>>>(ff, src2, g2, beta2, ff);
    // 10. degree / normalization
    deg_init_kernel<<<(N_NODES + 255) / 256, 256, 0, stream>>>(deg);
    deg_acc_kernel<<<(N_EDGES + 255) / 256, 256, 0, stream>>>(eirow, ea, deg);
    dis_kernel<<<(N_NODES + 255) / 256, 256, 0, stream>>>(deg, dis);
    // 11. counting sort of edges by destination row
    count_kernel<<<(N_EDGES + 255) / 256, 256, 0, stream>>>(eirow, cnt);
    scan_kernel<<<1, 1024, 0, stream>>>(cnt, rs, cur);
    scatter_kernel<<<(N_EDGES + 255) / 256, 256, 0, stream>>>(eirow, cur, sorted);
    // 12. aggregation
    agg_kernel<<<N_NODES, 256, 0, stream>>>(ff, eicol, ea, dis, rs, sorted, agg);
    // 13. out = relu(agg)@W_out + b_out (f32)
    gemm_mfma<float, 1, 0, 0><<<MT * (DOUT / 128), 256, 0, stream>>>(
        agg, wt_out, b_out, nullptr, outp, N_NODES, DOUT, DMODEL);
}

// Round 19
// 621.831 us; speedup vs baseline: 1.2049x; 1.2049x over previous
//
#include <hip/hip_runtime.h>

#define N_NODES 20000
#define N_EDGES 320000
#define DIN     256
#define DMODEL  512
#define TD      1536   // 3*D
#define FFD     2048
#define DOUT    128

typedef _Float16 f16;
typedef f16 f16x8 __attribute__((ext_vector_type(8)));
typedef f16 f16x4 __attribute__((ext_vector_type(4)));
typedef f16 f16x2 __attribute__((ext_vector_type(2)));
typedef float f32x4 __attribute__((ext_vector_type(4)));

__device__ __forceinline__ void cstore(float* p, float v) { *p = v; }
__device__ __forceinline__ void cstore(f16* p, float v)   { *p = (f16)v; }

#if defined(__has_builtin)
#if __has_builtin(__builtin_amdgcn_global_load_lds)
#define USE_GLOAD_LDS 1
#endif
#endif

// ---------------------------------------------------------------------------
// fp16 MFMA GEMM v5 (reverted: measured-best 611us config, round 15):
// 128x128 tile, BK=32, 4 waves, mfma_f32_16x16x32_f16. Triple-buffered
// K-loop, 2 tiles in flight (vmcnt(8)); raw s_barrier pair + counted vmcnt;
// pre-swizzled gload_lds source (m173). 1D grid + bijective XCD swizzle
// (n fastest -> A-panel L2 reuse; r15: FETCH 166->55MB).
// f16-C epilogue repacks through LDS -> coalesced f16x8 stores.
// A rows read unguarded to the 128-aligned tile edge (allocated slack).
// K%32==0 (K>=64), N%128==0, M guarded at C-write and addmat-read.
// ---------------------------------------------------------------------------
template<typename TC, int HAS_BIAS, int HAS_ADD, int DO_RELU>
__global__ __launch_bounds__(256)
void gemm_mfma(const f16* __restrict__ A, const f16* __restrict__ Bt,
               const float* __restrict__ bias, const float* __restrict__ addmat,
               TC* __restrict__ C, int M, int N, int K)
{
    __shared__ f16 smem[24576];   // 48KB: A bufs [0,12288), B bufs [12288,24576)
    const int tid  = threadIdx.x;
    const int lane = tid & 63;
    const int wid  = tid >> 6;
    const int wm = wid >> 1, wn = wid & 1;

    const int nwg  = gridDim.x;
    const int bid  = blockIdx.x;
    const int q    = nwg >> 3, rres = nwg & 7;
    const int xcd  = bid & 7,  slot = bid >> 3;
    const int wgid = (xcd < rres ? xcd * (q + 1)
                                 : rres * (q + 1) + (xcd - rres) * q) + slot;
    const int ntn  = N >> 7;
    const int m0 = (wgid / ntn) * 128, n0 = (wgid % ntn) * 128;

    f32x4 acc[4][4];
    #pragma unroll
    for (int i = 0; i < 4; ++i)
        #pragma unroll
        for (int j = 0; j < 4; ++j)
            acc[i][j] = (f32x4)0.0f;

    const int r  = lane & 15;
    const int kg = lane >> 4;
    const int px = (kg ^ ((r >> 1) & 3)) << 3;

#ifdef USE_GLOAD_LDS
    const int seg0 = wid * 2, seg1 = wid * 2 + 1;       // 16 rows each
    const int row0 = seg0 * 16 + (lane >> 2);
    const int row1 = seg1 * 16 + (lane >> 2);
    const int kc0  = (lane & 3) ^ ((row0 >> 1) & 3);    // pre-swizzled chunk
    const int kc1  = (lane & 3) ^ ((row1 >> 1) & 3);
    const f16* a0 = A  + (size_t)(m0 + row0) * K + kc0 * 8;
    const f16* a1 = A  + (size_t)(m0 + row1) * K + kc1 * 8;
    const f16* b0 = Bt + (size_t)(n0 + row0) * K + kc0 * 8;
    const f16* b1 = Bt + (size_t)(n0 + row1) * K + kc1 * 8;

    auto stage = [&](int buf, int k0) {
        f16* as = smem + buf * 4096;
        f16* bs = smem + 12288 + buf * 4096;
        __builtin_amdgcn_global_load_lds(
            (const __attribute__((address_space(1))) void*)(a0 + k0),
            (__attribute__((address_space(3))) void*)&as[seg0 * 512], 16, 0, 0);
        __builtin_amdgcn_global_load_lds(
            (const __attribute__((address_space(1))) void*)(a1 + k0),
            (__attribute__((address_space(3))) void*)&as[seg1 * 512], 16, 0, 0);
        __builtin_amdgcn_global_load_lds(
            (const __attribute__((address_space(1))) void*)(b0 + k0),
            (__attribute__((address_space(3))) void*)&bs[seg0 * 512], 16, 0, 0);
        __builtin_amdgcn_global_load_lds(
            (const __attribute__((address_space(1))) void*)(b1 + k0),
            (__attribute__((address_space(3))) void*)&bs[seg1 * 512], 16, 0, 0);
    };

    const int NT = K >> 5;
    stage(0, 0);
    if (NT > 1) stage(1, 32);
    for (int kt = 0; kt < NT; ++kt) {
        const int cur = kt % 3;
        if (kt + 2 < NT) {
            stage((kt + 2) % 3, (kt + 2) << 5);
            asm volatile("s_waitcnt vmcnt(8)" ::: "memory");  // tile kt landed
        } else if (kt + 1 < NT) {
            asm volatile("s_waitcnt vmcnt(4)" ::: "memory");
        } else {
            asm volatile("s_waitcnt vmcnt(0)" ::: "memory");
        }
        __builtin_amdgcn_s_barrier();
        __builtin_amdgcn_sched_barrier(0);
        const f16* as = smem + cur * 4096;
        const f16* bs = smem + 12288 + cur * 4096;
        f16x8 af[4], bfr[4];
        #pragma unroll
        for (int m = 0; m < 4; ++m)
            af[m] = *(const f16x8*)(&as[(wm * 64 + m * 16 + r) * 32 + px]);
        #pragma unroll
        for (int n = 0; n < 4; ++n)
            bfr[n] = *(const f16x8*)(&bs[(wn * 64 + n * 16 + r) * 32 + px]);
        #pragma unroll
        for (int m = 0; m < 4; ++m)
            #pragma unroll
            for (int n = 0; n < 4; ++n)
                acc[m][n] = __builtin_amdgcn_mfma_f32_16x16x32_f16(
                    af[m], bfr[n], acc[m][n], 0, 0, 0);
        __builtin_amdgcn_sched_barrier(0);
        __builtin_amdgcn_s_barrier();
    }
#else
    for (int k0 = 0; k0 < K; k0 += 32) {
        #pragma unroll
        for (int it = 0; it < 2; ++it) {
            const int c   = tid + it * 256;
            const int row = c >> 2, kc = c & 3;
            const int widx = row * 32 + ((kc ^ ((row >> 1) & 3)) << 3);
            f16x8 va = {0, 0, 0, 0, 0, 0, 0, 0};
            const int ga = m0 + row;
            if (ga < M) va = *(const f16x8*)(A + (size_t)ga * K + k0 + kc * 8);
            *(f16x8*)(&smem[widx]) = va;
            const f16x8 vb = *(const f16x8*)(Bt + (size_t)(n0 + row) * K + k0 + kc * 8);
            *(f16x8*)(&smem[12288 + widx]) = vb;
        }
        __syncthreads();
        f16x8 af[4], bfr[4];
        #pragma unroll
        for (int m = 0; m < 4; ++m)
            af[m] = *(const f16x8*)(&smem[(wm * 64 + m * 16 + r) * 32 + px]);
        #pragma unroll
        for (int n = 0; n < 4; ++n)
            bfr[n] = *(const f16x8*)(&smem[12288 + (wn * 64 + n * 16 + r) * 32 + px]);
        #pragma unroll
        for (int m = 0; m < 4; ++m)
            #pragma unroll
            for (int n = 0; n < 4; ++n)
                acc[m][n] = __builtin_amdgcn_mfma_f32_16x16x32_f16(
                    af[m], bfr[n], acc[m][n], 0, 0, 0);
        __syncthreads();
    }
#endif

    const int rq = lane >> 4;
    if constexpr (sizeof(TC) == 2) {
        // f16 output: repack via LDS (trailing barrier of last K-iter protects)
        #pragma unroll
        for (int m = 0; m < 4; ++m) {
            #pragma unroll
            for (int rr = 0; rr < 4; ++rr) {
                const int rl = wm * 64 + m * 16 + rq * 4 + rr;
                #pragma unroll
                for (int n = 0; n < 4; ++n) {
                    const int cl = wn * 64 + n * 16 + (lane & 15);
                    float v = acc[m][n][rr];
                    if (HAS_BIAS) v += bias[n0 + cl];
                    if (HAS_ADD && (m0 + rl) < M) v += addmat[(size_t)(m0 + rl) * N + n0 + cl];
                    if (DO_RELU) v = fmaxf(v, 0.f);
                    smem[rl * 128 + cl] = (f16)v;
                }
            }
        }
        __syncthreads();
        #pragma unroll
        for (int i = 0; i < 8; ++i) {
            const int ch  = tid + i * 256;          // 0..2047
            const int row = ch >> 4;
            const int cc  = (ch & 15) << 3;
            if (m0 + row < M)
                *(f16x8*)((f16*)C + (size_t)(m0 + row) * N + n0 + cc) =
                    *(const f16x8*)(&smem[row * 128 + cc]);
        }
    } else {
        #pragma unroll
        for (int m = 0; m < 4; ++m) {
            #pragma unroll
            for (int rr = 0; rr < 4; ++rr) {
                const int row = m0 + wm * 64 + m * 16 + rq * 4 + rr;
                if (row >= M) continue;
                #pragma unroll
                for (int n = 0; n < 4; ++n) {
                    const int col = n0 + wn * 64 + n * 16 + (lane & 15);
                    float v = acc[m][n][rr];
                    if (HAS_BIAS) v += bias[col];
                    if (HAS_ADD)  v += addmat[(size_t)row * N + col];
                    if (DO_RELU)  v = fmaxf(v, 0.f);
                    cstore(&C[(size_t)row * N + col], v);
                }
            }
        }
    }
}

// ---------------------------------------------------------------------------
// Weight transpose+convert: W[K][N] f32 -> Wt[N][K] f16. 32x32 LDS tiles.
// ---------------------------------------------------------------------------
__global__ void wt_kernel(const float* __restrict__ W, f16* __restrict__ Wt, int K, int N)
{
    __shared__ float t[32][33];
    const int k0 = blockIdx.x * 32, n0 = blockIdx.y * 32;
    const int tx = threadIdx.x & 31, ty = threadIdx.x >> 5;
    #pragma unroll
    for (int i = ty; i < 32; i += 8) {
        const int k = k0 + i;
        if (k < K && n0 + tx < N) t[i][tx] = W[(size_t)k * N + n0 + tx];
    }
    __syncthreads();
    #pragma unroll
    for (int i = ty; i < 32; i += 8) {
        const int n = n0 + i;
        if (n < N && k0 + tx < K) Wt[(size_t)n * K + k0 + tx] = (f16)t[tx][i];
    }
}

// f32 -> f16 elementwise (n % 4 == 0); also initializes deg[0..N_NODES)=1.
__global__ void f2h_kernel(const float* __restrict__ in, f16* __restrict__ out, int n,
                           float* __restrict__ deg)
{
    const int gid = blockIdx.x * 256 + threadIdx.x;
    if (gid < N_NODES) deg[gid] = 1.0f;   // self-loop weight
    const int i = gid * 4;
    if (i < n) {
        const float4 v = *(const float4*)(in + i);
        out[i + 0] = (f16)v.x; out[i + 1] = (f16)v.y;
        out[i + 2] = (f16)v.z; out[i + 3] = (f16)v.w;
    }
}

// ---------------------------------------------------------------------------
// Fused conv + kv-sum + q materialization (unchanged).
// ---------------------------------------------------------------------------
#define KV_CHUNK 32
#define KV_BLOCKS (N_NODES / KV_CHUNK)   // 625
__global__ __launch_bounds__(256, 2)
void kv_fused_kernel(const f16* __restrict__ qkv, const float* __restrict__ cw,
                     f16* __restrict__ q_all, float* __restrict__ kvg,
                     float* __restrict__ kv_part)
{
    __shared__ f16 rows[5][TD];
    const int tid = threadIdx.x;
    const int n0 = blockIdx.x * KV_CHUNK;
    const int h = tid >> 1, d0 = (tid & 1) * 4;

    float wk[4][5], wv[8][5], wq[8][5];
    if (h >= 64) {
        const int cb = (h - 64) * 24;
        #pragma unroll
        for (int dd = 0; dd < 4; ++dd)
            #pragma unroll
            for (int t = 0; t < 5; ++t)
                wk[dd][t] = cw[(cb + 8 + d0 + dd) * 5 + t];
        #pragma unroll
        for (int e = 0; e < 8; ++e)
            #pragma unroll
            for (int t = 0; t < 5; ++t)
                wv[e][t] = cw[(cb + 16 + e) * 5 + t];
    }
    if (tid >= 64 && tid < 128) {
        const int cb = (tid - 64) * 24;
        #pragma unroll
        for (int d = 0; d < 8; ++d)
            #pragma unroll
            for (int t = 0; t < 5; ++t)
                wq[d][t] = cw[(cb + d) * 5 + t];
    }

    for (int r = n0 - 2; r <= n0 + 2; ++r) {
        const int slot = ((r % 5) + 5) % 5;
        if (tid < 192) {
            f16x8 v = {0, 0, 0, 0, 0, 0, 0, 0};
            if (r >= 0 && r < N_NODES)
                v = *(const f16x8*)(qkv + (size_t)r * TD + tid * 8);
            *(f16x8*)(&rows[slot][tid * 8]) = v;
        }
    }
    __syncthreads();

    float acc[36] = {};

    for (int i = 0; i < KV_CHUNK; ++i) {
        const int n = n0 + i;

        f16x8 pre = {0, 0, 0, 0, 0, 0, 0, 0};
        const bool doPre = (i < KV_CHUNK - 1) && (tid < 192);
        if (doPre && (n + 3) < N_NODES)
            pre = *(const f16x8*)(qkv + (size_t)(n + 3) * TD + tid * 8);

        const f16* wr[5] = { rows[(((n - 2) % 5) + 5) % 5],
                             rows[(((n - 1) % 5) + 5) % 5],
                             rows[n % 5],
                             rows[(n + 1) % 5],
                             rows[(n + 2) % 5] };

        float kv4[4], vv[8];
        if (h < 64) {
            const int cb = h * 24;
            const f16x4 kd = *(const f16x4*)(wr[2] + cb + 8 + d0);
            const f16x8 vd = *(const f16x8*)(wr[2] + cb + 16);
            #pragma unroll
            for (int dd = 0; dd < 4; ++dd) kv4[dd] = fmaxf((float)kd[dd], 0.f);
            #pragma unroll
            for (int e = 0; e < 8; ++e) vv[e] = (float)vd[e];
        } else {
            const int cb = (h - 64) * 24;
            f16x4 ka[5]; f16x8 va[5];
            #pragma unroll
            for (int t = 0; t < 5; ++t) {
                ka[t] = *(const f16x4*)(wr[t] + cb + 8 + d0);
                va[t] = *(const f16x8*)(wr[t] + cb + 16);
            }
            #pragma unroll
            for (int dd = 0; dd < 4; ++dd) {
                float s = 0.f;
                #pragma unroll
                for (int t = 0; t < 5; ++t) s = fmaf(wk[dd][t], (float)ka[t][dd], s);
                kv4[dd] = fmaxf(s, 0.f);
            }
            #pragma unroll
            for (int e = 0; e < 8; ++e) {
                float s = 0.f;
                #pragma unroll
                for (int t = 0; t < 5; ++t) s = fmaf(wv[e][t], (float)va[t][e], s);
                vv[e] = s;
            }
        }
        #pragma unroll
        for (int dd = 0; dd < 4; ++dd) {
            #pragma unroll
            for (int e = 0; e < 8; ++e)
                acc[dd * 9 + e] = fmaf(kv4[dd], vv[e], acc[dd * 9 + e]);
            acc[dd * 9 + 8] += kv4[dd];
        }

        if (tid < 128) {
            f16x8 qv;
            if (tid < 64) {
                qv = *(const f16x8*)(wr[2] + tid * 24);
                #pragma unroll
                for (int d = 0; d < 8; ++d)
                    qv[d] = qv[d] > (f16)0 ? qv[d] : (f16)0;
            } else {
                const int cb = (tid - 64) * 24;
                f16x8 qa[5];
                #pragma unroll
                for (int t = 0; t < 5; ++t) qa[t] = *(const f16x8*)(wr[t] + cb);
                #pragma unroll
                for (int d = 0; d < 8; ++d) {
                    float s = 0.f;
                    #pragma unroll
                    for (int t = 0; t < 5; ++t) s = fmaf(wq[d][t], (float)qa[t][d], s);
                    qv[d] = (f16)fmaxf(s, 0.f);
                }
            }
            *(f16x8*)(q_all + (size_t)n * 1024 + tid * 8) = qv;
        }

        __syncthreads();
        if (doPre)
            *(f16x8*)(&rows[(n + 3) % 5][tid * 8]) = pre;
        __syncthreads();
    }

    if (kv_part) {
        float* dst = kv_part + (size_t)blockIdx.x * 9216 + tid * 36;
        #pragma unroll
        for (int i = 0; i < 36; ++i) dst[i] = acc[i];
    } else {
        #pragma unroll
        for (int dd = 0; dd < 4; ++dd)
            #pragma unroll
            for (int e = 0; e < 9; ++e)
                atomicAdd(&kvg[h * 72 + (d0 + dd) * 9 + e], acc[dd * 9 + e]);
    }
}

// kvg[j] = sum_b kv_part[b][j], j in [0,9216). Grid: 36 x 256.
__global__ void kv_reduce_kernel(const float* __restrict__ kv_part,
                                 float* __restrict__ kvg)
{
    const int j = blockIdx.x * 256 + threadIdx.x;
    float s = 0.f;
    for (int b = 0; b < KV_BLOCKS; ++b)
        s += kv_part[(size_t)b * 9216 + j];
    kvg[j] = s;
}

// ---------------------------------------------------------------------------
// o[n, h*8+e] = (sum_d q*kv[h,d,e]) / (sum_d q*kv[h,d,8] + 1e-15)
// ---------------------------------------------------------------------------
__global__ __launch_bounds__(256)
void attn_o_kernel(const f16* __restrict__ q_all, const float* __restrict__ kvg,
                   f16* __restrict__ o)
{
    __shared__ float kvt[72][128];   // [d*9+e][h]
    const int tid = threadIdx.x;
    for (int i = tid; i < 9216; i += 256) {
        const int hh = i & 127, j = i >> 7;
        kvt[j][hh] = kvg[hh * 72 + j];
    }
    __syncthreads();
    const int h = tid & 127, sub = tid >> 7;
    for (int nb = blockIdx.x; nb < N_NODES / 2; nb += gridDim.x) {
        const int n = nb * 2 + sub;
        const f16x8 qv8 = *(const f16x8*)(q_all + (size_t)n * 1024 + h * 8);
        float q[8];
        #pragma unroll
        for (int d = 0; d < 8; ++d) q[d] = (float)qv8[d];
        float num[8], den = 0.f;
        #pragma unroll
        for (int e = 0; e < 8; ++e) {
            float s = 0.f;
            #pragma unroll
            for (int d = 0; d < 8; ++d) s = fmaf(q[d], kvt[d * 9 + e][h], s);
            num[e] = s;
        }
        #pragma unroll
        for (int d = 0; d < 8; ++d) den = fmaf(q[d], kvt[d * 9 + 8][h], den);
        const float rinv = 1.f / (den + 1e-15f);
        f16x8 ov;
        #pragma unroll
        for (int e = 0; e < 8; ++e) ov[e] = (f16)(num[e] * rinv);
        *(f16x8*)(o + (size_t)n * 1024 + h * 8) = ov;
    }
}

// ---------------------------------------------------------------------------
// out_h = f16(resid + LN(y)*g + b). resid f16. out_h may alias y.
// ---------------------------------------------------------------------------
__global__ void ln_res_kernel(const f16* __restrict__ y, const f16* __restrict__ resid,
                              const float* __restrict__ g, const float* __restrict__ b,
                              f16* __restrict__ out_h)
{
    const int row = blockIdx.x;
    const int tid = threadIdx.x;
    const f16* yr = y + (size_t)row * DMODEL;
    const float v0 = (float)yr[tid], v1 = (float)yr[tid + 256];
    __shared__ float red[4], red2[4];
    float s = v0 + v1;
    #pragma unroll
    for (int o = 32; o > 0; o >>= 1) s += __shfl_down(s, o);
    if ((tid & 63) == 0) red[tid >> 6] = s;
    __syncthreads();
    const float mean = (red[0] + red[1] + red[2] + red[3]) * (1.0f / DMODEL);
    const float d0 = v0 - mean, d1 = v1 - mean;
    float q = d0 * d0 + d1 * d1;
    #pragma unroll
    for (int o = 32; o > 0; o >>= 1) q += __shfl_down(q, o);
    if ((tid & 63) == 0) red2[tid >> 6] = q;
    __syncthreads();
    const float var = (red2[0] + red2[1] + red2[2] + red2[3]) * (1.0f / DMODEL);
    const float inv = rsqrtf(var + 1e-5f);
    const f16* rr = resid + (size_t)row * DMODEL;
    const float o0 = (float)rr[tid]       + d0 * inv * g[tid]       + b[tid];
    const float o1 = (float)rr[tid + 256] + d1 * inv * g[tid + 256] + b[tid + 256];
    f16* oh = out_h + (size_t)row * DMODEL;
    oh[tid] = (f16)o0;
    oh[tid + 256] = (f16)o1;
}

// ---------------------------------------------------------------------------
// Graph prep (fused): one edge pass does deg-accum + count.
// ---------------------------------------------------------------------------
__global__ void edge_prep_kernel(const int* __restrict__ eirow, const float* __restrict__ ea,
                                 float* __restrict__ deg, int* __restrict__ cnt)
{
    const int e = blockIdx.x * 256 + threadIdx.x;
    if (e < N_EDGES) {
        const int r = eirow[e];
        atomicAdd(&deg[r], ea[e]);
        atomicAdd(&cnt[r], 1);
    }
}

// Single-block scan of cnt -> rowstart/cursor; also dis = rsqrt(deg) (fused).
__global__ void scan_kernel(const int* __restrict__ cnt, int* __restrict__ rowstart,
                            int* __restrict__ cursor, const float* __restrict__ deg,
                            float* __restrict__ dis)
{
    __shared__ int ls[1024];
    const int tid = threadIdx.x;
    const int base = tid * 20;
    int local[20];
    int s = 0;
    #pragma unroll
    for (int i = 0; i < 20; ++i) {
        const int idx = base + i;
        const int v = (idx < N_NODES) ? cnt[idx] : 0;
        local[i] = s;
        s += v;
        if (idx < N_NODES) dis[idx] = rsqrtf(deg[idx]);   // deg >= 1 always
    }
    ls[tid] = s;
    __syncthreads();
    for (int off = 1; off < 1024; off <<= 1) {
        const int v = (tid >= off) ? ls[tid - off] : 0;
        __syncthreads();
        ls[tid] += v;
        __syncthreads();
    }
    const int excl = (tid == 0) ? 0 : ls[tid - 1];
    #pragma unroll
    for (int i = 0; i < 20; ++i) {
        const int idx = base + i;
        if (idx < N_NODES) {
            const int st = excl + local[i];
            rowstart[idx] = st;
            cursor[idx] = st;
        }
    }
    if (tid == 1023) rowstart[N_NODES] = ls[1023];
}

__global__ void scatter_kernel(const int* __restrict__ eirow, int* __restrict__ cursor,
                               int* __restrict__ sorted)
{
    const int e = blockIdx.x * 256 + threadIdx.x;
    if (e < N_EDGES) {
        const int r = eirow[e];
        const int p = atomicAdd(&cursor[r], 1);
        sorted[p] = e;
    }
}

// ---------------------------------------------------------------------------
// Aggregation v3 (unchanged): LDS metadata prefetch + 4-wave row gathers.
// ---------------------------------------------------------------------------
__global__ __launch_bounds__(256)
void agg_kernel(const f16* __restrict__ srcf_h, const int* __restrict__ eicol,
                const float* __restrict__ ea, const float* __restrict__ dis,
                const int* __restrict__ rowstart, const int* __restrict__ sorted,
                f16* __restrict__ agg)
{
    __shared__ int   cbuf[256];
    __shared__ float wbuf[256];
    __shared__ float part[4][512];
    const int i = blockIdx.x;
    const int tid = threadIdx.x;
    const int lane = tid & 63, wv = tid >> 6;
    const float di = dis[i];
    const int s = rowstart[i];
    const int deg = rowstart[i + 1] - s;

    float acc[8] = {};
    for (int base = 0; base < deg; base += 256) {
        const int m = min(256, deg - base);
        if (tid < m) {
            const int e = sorted[s + base + tid];
            const int c = eicol[e];
            cbuf[tid] = c;
            wbuf[tid] = di * ea[e] * dis[c];
        }
        __syncthreads();
        #pragma unroll 2
        for (int p = wv; p < m; p += 4) {
            const int c = cbuf[p];
            const float w = wbuf[p];
            const f16x8 v = *(const f16x8*)(srcf_h + (size_t)c * DMODEL + lane * 8);
            #pragma unroll
            for (int j = 0; j < 8; ++j) acc[j] = fmaf(w, (float)v[j], acc[j]);
        }
        __syncthreads();
    }
    #pragma unroll
    for (int j = 0; j < 8; ++j) part[wv][lane * 8 + j] = acc[j];
    __syncthreads();
    const float wself = di * di;
    const f16x2 vs = *(const f16x2*)(srcf_h + (size_t)i * DMODEL + tid * 2);
    float a0 = wself * (float)vs[0], a1 = wself * (float)vs[1];
    #pragma unroll
    for (int w = 0; w < 4; ++w) {
        a0 += part[w][tid * 2];
        a1 += part[w][tid * 2 + 1];
    }
    f16x2 o;
    o[0] = (f16)fmaxf(a0, 0.f);
    o[1] = (f16)fmaxf(a1, 0.f);
    *(f16x2*)(agg + (size_t)i * DMODEL + tid * 2) = o;
}

// ---------------------------------------------------------------------------
// Workspace layout (bytes) — unchanged from rounds 12-18.
// ---------------------------------------------------------------------------
static constexpr size_t OFF_HH    = 0;              // f16 20,480,000
static constexpr size_t OFF_FF    = 20480000ull;    // f16 20,480,000
static constexpr size_t OFF_QKV   = 40960000ull;    // f16 61,440,000
static constexpr size_t OFF_SRC2  = 40960000ull;    // f16 20,480,000 (alias)
static constexpr size_t OFF_FFH   = 61440000ull;    // f16 81,920,000 (alias)
static constexpr size_t OFF_AGG   = 61440000ull;    // f16 40,960,000 (alias)
static constexpr size_t OFF_XH    = 102400000ull;   // f16 10,240,000
static constexpr size_t OFF_ATTN  = 102400000ull;   // f16 40,960,000 (alias)
static constexpr size_t WT_IN     = 143360000ull;
static constexpr size_t WT_QKV    = 143622144ull;
static constexpr size_t WT_PROJ   = 145195008ull;
static constexpr size_t WT_W1     = 146243584ull;
static constexpr size_t WT_W2     = 148340736ull;
static constexpr size_t WT_OUT    = 150437888ull;
static constexpr size_t OFF_KV    = 150568960ull;
static constexpr size_t OFF_DEG   = 150605824ull;
static constexpr size_t OFF_DIS   = 150685824ull;
static constexpr size_t OFF_RS    = 150765824ull;
static constexpr size_t OFF_CUR   = 150845888ull;
static constexpr size_t OFF_CNT   = 150925888ull;
static constexpr size_t OFF_SORT  = 151005888ull;   // -> 152,285,888
static constexpr size_t OFF_KVP   = 152285888ull;   // -> 175,325,888
static constexpr size_t WS_NEED_KVP = 175325888ull;

extern "C" void kernel_launch(void* const* d_in, const int* in_sizes, int n_in,
                              void* d_out, int out_size, void* d_ws, size_t ws_size,
                              hipStream_t stream)
{
    const float* x      = (const float*)d_in[0];
    const int*   ei     = (const int*)d_in[1];
    const float* ea     = (const float*)d_in[2];
    const float* pe     = (const float*)d_in[4];
    const float* W_in   = (const float*)d_in[5];
    const float* b_in   = (const float*)d_in[6];
    const float* W_qkv  = (const float*)d_in[7];
    const float* conv_w = (const float*)d_in[8];
    const float* W_proj = (const float*)d_in[9];
    const float* b_proj = (const float*)d_in[10];
    const float* g1     = (const float*)d_in[11];
    const float* beta1  = (const float*)d_in[12];
    const float* W1     = (const float*)d_in[13];
    const float* bf1    = (const float*)d_in[14];
    const float* W2     = (const float*)d_in[15];
    const float* bf2    = (const float*)d_in[16];
    const float* g2     = (const float*)d_in[17];
    const float* beta2  = (const float*)d_in[18];
    const float* W_out  = (const float*)d_in[19];
    const float* b_out  = (const float*)d_in[20];

    char* ws = (char*)d_ws;
    f16*   h_h    = (f16*)(ws + OFF_HH);
    f16*   ff     = (f16*)(ws + OFF_FF);
    f16*   qkv    = (f16*)(ws + OFF_QKV);
    f16*   src2   = (f16*)(ws + OFF_SRC2);
    f16*   ffh    = (f16*)(ws + OFF_FFH);
    f16*   agg    = (f16*)(ws + OFF_AGG);
    f16*   x_h    = (f16*)(ws + OFF_XH);
    f16*   q_all  = (f16*)(ws + OFF_ATTN);
    f16*   wt_in   = (f16*)(ws + WT_IN);
    f16*   wt_qkv  = (f16*)(ws + WT_QKV);
    f16*   wt_proj = (f16*)(ws + WT_PROJ);
    f16*   wt_w1   = (f16*)(ws + WT_W1);
    f16*   wt_w2   = (f16*)(ws + WT_W2);
    f16*   wt_out  = (f16*)(ws + WT_OUT);
    float* kvg    = (float*)(ws + OFF_KV);
    float* deg    = (float*)(ws + OFF_DEG);
    float* dis    = (float*)(ws + OFF_DIS);
    int*   rs     = (int*)(ws + OFF_RS);
    int*   cur    = (int*)(ws + OFF_CUR);
    int*   cnt    = (int*)(ws + OFF_CNT);
    int*   sorted = (int*)(ws + OFF_SORT);
    float* outp   = (float*)d_out;

    const bool twoStage = (ws_size >= WS_NEED_KVP);
    float* kv_part = twoStage ? (float*)(ws + OFF_KVP) : nullptr;

    const int* eirow = ei;
    const int* eicol = ei + N_EDGES;

    if (!twoStage)
        hipMemsetAsync(kvg, 0, 9216 * sizeof(float), stream);
    hipMemsetAsync(cnt, 0, N_NODES * sizeof(int), stream);

    // 0. weight transpose+convert (f32 [K][N] -> f16 [N][K])
    wt_kernel<<<dim3(DIN / 32,   DMODEL / 32), 256, 0, stream>>>(W_in,   wt_in,   DIN,    DMODEL);
    wt_kernel<<<dim3(DMODEL / 32, TD / 32),    256, 0, stream>>>(W_qkv,  wt_qkv,  DMODEL, TD);
    wt_kernel<<<dim3(1024 / 32,  DMODEL / 32), 256, 0, stream>>>(W_proj, wt_proj, 1024,   DMODEL);
    wt_kernel<<<dim3(DMODEL / 32, FFD / 32),   256, 0, stream>>>(W1,     wt_w1,   DMODEL, FFD);
    wt_kernel<<<dim3(FFD / 32,   DMODEL / 32), 256, 0, stream>>>(W2,     wt_w2,   FFD,    DMODEL);
    wt_kernel<<<dim3(DMODEL / 32, DOUT / 32),  256, 0, stream>>>(W_out,  wt_out,  DMODEL, DOUT);
    // 0b. x -> f16 (+ deg init fused)
    f2h_kernel<<<(N_NODES * DIN) / 1024, 256, 0, stream>>>(x, x_h, N_NODES * DIN, deg);

    const int MT = (N_NODES + 127) / 128;   // 157

    // 1. h_h = f16(x@W_in + b_in + pe)
    gemm_mfma<f16, 1, 1, 0><<<MT * (DMODEL / 128), 256, 0, stream>>>(
        x_h, wt_in, b_in, pe, h_h, N_NODES, DMODEL, DIN);
    // 2. qkv = h_h@W_qkv (f16)
    gemm_mfma<f16, 0, 0, 0><<<MT * (TD / 128), 256, 0, stream>>>(
        h_h, wt_qkv, nullptr, nullptr, qkv, N_NODES, TD, DMODEL);
    // 3. fused conv + kv partials + q materialization
    kv_fused_kernel<<<KV_BLOCKS, 256, 0, stream>>>(qkv, conv_w, q_all, kvg, kv_part);
    if (twoStage)
        kv_reduce_kernel<<<36, 256, 0, stream>>>(kv_part, kvg);
    // 4. attention readout (in-place over q_all)
    attn_o_kernel<<<2500, 256, 0, stream>>>(q_all, kvg, q_all);
    // 5. src2 = attn_o@W_proj + b_proj (f16)
    gemm_mfma<f16, 1, 0, 0><<<MT * (DMODEL / 128), 256, 0, stream>>>(
        q_all, wt_proj, b_proj, nullptr, src2, N_NODES, DMODEL, 1024);
    // 6. src2 = f16(h_h + LN(src2))  (in-place)
    ln_res_kernel<<<N_NODES, 256, 0, stream>>>(src2, h_h, g1, beta1, src2);
    // 7. ffh = relu(src2@W1 + bf1) (f16)
    gemm_mfma<f16, 1, 0, 1><<<MT * (FFD / 128), 256, 0, stream>>>(
        src2, wt_w1, bf1, nullptr, ffh, N_NODES, FFD, DMODEL);
    // 8. ff = ffh@W2 + bf2 (f16)
    gemm_mfma<f16, 1, 0, 0><<<MT * (DMODEL / 128), 256, 0, stream>>>(
        ffh, wt_w2, bf2, nullptr, ff, N_NODES, DMODEL, FFD);
    // 9. ff = f16(src2 + LN(ff))  (in-place; agg gather source)
    ln_res_kernel<<<N_NODES, 256, 0, stream>>>(ff, src2, g2, beta2, ff);
    // 10. fused edge pass: deg accumulation + per-row count
    edge_prep_kernel<<<(N_EDGES + 255) / 256, 256, 0, stream>>>(eirow, ea, deg, cnt);
    // 11. scan (+ dis fused) and scatter (counting sort by destination row)
    scan_kernel<<<1, 1024, 0, stream>>>(cnt, rs, cur, deg, dis);
    scatter_kernel<<<(N_EDGES + 255) / 256, 256, 0, stream>>>(eirow, cur, sorted);
    // 12. aggregation
    agg_kernel<<<N_NODES, 256, 0, stream>>>(ff, eicol, ea, dis, rs, sorted, agg);
    // 13. out = relu(agg)@W_out + b_out (f32)
    gemm_mfma<float, 1, 0, 0><<<MT * (DOUT / 128), 256, 0, stream>>>(
        agg, wt_out, b_out, nullptr, outp, N_NODES, DOUT, DMODEL);
}

// Round 21
// 617.922 us; speedup vs baseline: 1.2125x; 1.0063x over previous
//
#include <hip/hip_runtime.h>

#define N_NODES 20000
#define N_EDGES 320000
#define DIN     256
#define DMODEL  512
#define TD      1536   // 3*D
#define FFD     2048
#define DOUT    128

typedef _Float16 f16;
typedef f16 f16x8 __attribute__((ext_vector_type(8)));
typedef f16 f16x4 __attribute__((ext_vector_type(4)));
typedef f16 f16x2 __attribute__((ext_vector_type(2)));
typedef float f32x4 __attribute__((ext_vector_type(4)));

__device__ __forceinline__ void cstore(float* p, float v) { *p = v; }
__device__ __forceinline__ void cstore(f16* p, float v)   { *p = (f16)v; }

#if defined(__has_builtin)
#if __has_builtin(__builtin_amdgcn_global_load_lds)
#define USE_GLOAD_LDS 1
#endif
#endif

// ---------------------------------------------------------------------------
// fp16 MFMA GEMM v5 (measured-best validated config, rounds 15/19):
// 128x128 tile, BK=32, 4 waves, mfma_f32_16x16x32_f16. Triple-buffered
// K-loop, 2 tiles in flight (vmcnt(8)); raw s_barrier pair + counted vmcnt;
// pre-swizzled gload_lds source (m173). 1D grid + bijective XCD swizzle
// (n fastest -> A-panel L2 reuse; r15: FETCH 166->55MB).
// f16-C epilogue repacks through LDS -> coalesced f16x8 stores.
// A rows read unguarded to the 128-aligned tile edge (allocated slack).
// K%32==0 (K>=64), N%128==0, M guarded at C-write and addmat-read.
// ---------------------------------------------------------------------------
template<typename TC, int HAS_BIAS, int HAS_ADD, int DO_RELU>
__global__ __launch_bounds__(256)
void gemm_mfma(const f16* __restrict__ A, const f16* __restrict__ Bt,
               const float* __restrict__ bias, const float* __restrict__ addmat,
               TC* __restrict__ C, int M, int N, int K)
{
    __shared__ f16 smem[24576];   // 48KB: A bufs [0,12288), B bufs [12288,24576)
    const int tid  = threadIdx.x;
    const int lane = tid & 63;
    const int wid  = tid >> 6;
    const int wm = wid >> 1, wn = wid & 1;

    const int nwg  = gridDim.x;
    const int bid  = blockIdx.x;
    const int q    = nwg >> 3, rres = nwg & 7;
    const int xcd  = bid & 7,  slot = bid >> 3;
    const int wgid = (xcd < rres ? xcd * (q + 1)
                                 : rres * (q + 1) + (xcd - rres) * q) + slot;
    const int ntn  = N >> 7;
    const int m0 = (wgid / ntn) * 128, n0 = (wgid % ntn) * 128;

    f32x4 acc[4][4];
    #pragma unroll
    for (int i = 0; i < 4; ++i)
        #pragma unroll
        for (int j = 0; j < 4; ++j)
            acc[i][j] = (f32x4)0.0f;

    const int r  = lane & 15;
    const int kg = lane >> 4;
    const int px = (kg ^ ((r >> 1) & 3)) << 3;

#ifdef USE_GLOAD_LDS
    const int seg0 = wid * 2, seg1 = wid * 2 + 1;       // 16 rows each
    const int row0 = seg0 * 16 + (lane >> 2);
    const int row1 = seg1 * 16 + (lane >> 2);
    const int kc0  = (lane & 3) ^ ((row0 >> 1) & 3);    // pre-swizzled chunk
    const int kc1  = (lane & 3) ^ ((row1 >> 1) & 3);
    const f16* a0 = A  + (size_t)(m0 + row0) * K + kc0 * 8;
    const f16* a1 = A  + (size_t)(m0 + row1) * K + kc1 * 8;
    const f16* b0 = Bt + (size_t)(n0 + row0) * K + kc0 * 8;
    const f16* b1 = Bt + (size_t)(n0 + row1) * K + kc1 * 8;

    auto stage = [&](int buf, int k0) {
        f16* as = smem + buf * 4096;
        f16* bs = smem + 12288 + buf * 4096;
        __builtin_amdgcn_global_load_lds(
            (const __attribute__((address_space(1))) void*)(a0 + k0),
            (__attribute__((address_space(3))) void*)&as[seg0 * 512], 16, 0, 0);
        __builtin_amdgcn_global_load_lds(
            (const __attribute__((address_space(1))) void*)(a1 + k0),
            (__attribute__((address_space(3))) void*)&as[seg1 * 512], 16, 0, 0);
        __builtin_amdgcn_global_load_lds(
            (const __attribute__((address_space(1))) void*)(b0 + k0),
            (__attribute__((address_space(3))) void*)&bs[seg0 * 512], 16, 0, 0);
        __builtin_amdgcn_global_load_lds(
            (const __attribute__((address_space(1))) void*)(b1 + k0),
            (__attribute__((address_space(3))) void*)&bs[seg1 * 512], 16, 0, 0);
    };

    const int NT = K >> 5;
    stage(0, 0);
    if (NT > 1) stage(1, 32);
    for (int kt = 0; kt < NT; ++kt) {
        const int cur = kt % 3;
        if (kt + 2 < NT) {
            stage((kt + 2) % 3, (kt + 2) << 5);
            asm volatile("s_waitcnt vmcnt(8)" ::: "memory");  // tile kt landed
        } else if (kt + 1 < NT) {
            asm volatile("s_waitcnt vmcnt(4)" ::: "memory");
        } else {
            asm volatile("s_waitcnt vmcnt(0)" ::: "memory");
        }
        __builtin_amdgcn_s_barrier();
        __builtin_amdgcn_sched_barrier(0);
        const f16* as = smem + cur * 4096;
        const f16* bs = smem + 12288 + cur * 4096;
        f16x8 af[4], bfr[4];
        #pragma unroll
        for (int m = 0; m < 4; ++m)
            af[m] = *(const f16x8*)(&as[(wm * 64 + m * 16 + r) * 32 + px]);
        #pragma unroll
        for (int n = 0; n < 4; ++n)
            bfr[n] = *(const f16x8*)(&bs[(wn * 64 + n * 16 + r) * 32 + px]);
        #pragma unroll
        for (int m = 0; m < 4; ++m)
            #pragma unroll
            for (int n = 0; n < 4; ++n)
                acc[m][n] = __builtin_amdgcn_mfma_f32_16x16x32_f16(
                    af[m], bfr[n], acc[m][n], 0, 0, 0);
        __builtin_amdgcn_sched_barrier(0);
        __builtin_amdgcn_s_barrier();
    }
#else
    for (int k0 = 0; k0 < K; k0 += 32) {
        #pragma unroll
        for (int it = 0; it < 2; ++it) {
            const int c   = tid + it * 256;
            const int row = c >> 2, kc = c & 3;
            const int widx = row * 32 + ((kc ^ ((row >> 1) & 3)) << 3);
            f16x8 va = {0, 0, 0, 0, 0, 0, 0, 0};
            const int ga = m0 + row;
            if (ga < M) va = *(const f16x8*)(A + (size_t)ga * K + k0 + kc * 8);
            *(f16x8*)(&smem[widx]) = va;
            const f16x8 vb = *(const f16x8*)(Bt + (size_t)(n0 + row) * K + k0 + kc * 8);
            *(f16x8*)(&smem[12288 + widx]) = vb;
        }
        __syncthreads();
        f16x8 af[4], bfr[4];
        #pragma unroll
        for (int m = 0; m < 4; ++m)
            af[m] = *(const f16x8*)(&smem[(wm * 64 + m * 16 + r) * 32 + px]);
        #pragma unroll
        for (int n = 0; n < 4; ++n)
            bfr[n] = *(const f16x8*)(&smem[12288 + (wn * 64 + n * 16 + r) * 32 + px]);
        #pragma unroll
        for (int m = 0; m < 4; ++m)
            #pragma unroll
            for (int n = 0; n < 4; ++n)
                acc[m][n] = __builtin_amdgcn_mfma_f32_16x16x32_f16(
                    af[m], bfr[n], acc[m][n], 0, 0, 0);
        __syncthreads();
    }
#endif

    const int rq = lane >> 4;
    if constexpr (sizeof(TC) == 2) {
        // f16 output: repack via LDS (trailing barrier of last K-iter protects)
        #pragma unroll
        for (int m = 0; m < 4; ++m) {
            #pragma unroll
            for (int rr = 0; rr < 4; ++rr) {
                const int rl = wm * 64 + m * 16 + rq * 4 + rr;
                #pragma unroll
                for (int n = 0; n < 4; ++n) {
                    const int cl = wn * 64 + n * 16 + (lane & 15);
                    float v = acc[m][n][rr];
                    if (HAS_BIAS) v += bias[n0 + cl];
                    if (HAS_ADD && (m0 + rl) < M) v += addmat[(size_t)(m0 + rl) * N + n0 + cl];
                    if (DO_RELU) v = fmaxf(v, 0.f);
                    smem[rl * 128 + cl] = (f16)v;
                }
            }
        }
        __syncthreads();
        #pragma unroll
        for (int i = 0; i < 8; ++i) {
            const int ch  = tid + i * 256;          // 0..2047
            const int row = ch >> 4;
            const int cc  = (ch & 15) << 3;
            if (m0 + row < M)
                *(f16x8*)((f16*)C + (size_t)(m0 + row) * N + n0 + cc) =
                    *(const f16x8*)(&smem[row * 128 + cc]);
        }
    } else {
        #pragma unroll
        for (int m = 0; m < 4; ++m) {
            #pragma unroll
            for (int rr = 0; rr < 4; ++rr) {
                const int row = m0 + wm * 64 + m * 16 + rq * 4 + rr;
                if (row >= M) continue;
                #pragma unroll
                for (int n = 0; n < 4; ++n) {
                    const int col = n0 + wn * 64 + n * 16 + (lane & 15);
                    float v = acc[m][n][rr];
                    if (HAS_BIAS) v += bias[col];
                    if (HAS_ADD)  v += addmat[(size_t)row * N + col];
                    if (DO_RELU)  v = fmaxf(v, 0.f);
                    cstore(&C[(size_t)row * N + col], v);
                }
            }
        }
    }
}

// ---------------------------------------------------------------------------
// Weight transpose+convert: W[K][N] f32 -> Wt[N][K] f16. 32x32 LDS tiles.
// ---------------------------------------------------------------------------
__global__ void wt_kernel(const float* __restrict__ W, f16* __restrict__ Wt, int K, int N)
{
    __shared__ float t[32][33];
    const int k0 = blockIdx.x * 32, n0 = blockIdx.y * 32;
    const int tx = threadIdx.x & 31, ty = threadIdx.x >> 5;
    #pragma unroll
    for (int i = ty; i < 32; i += 8) {
        const int k = k0 + i;
        if (k < K && n0 + tx < N) t[i][tx] = W[(size_t)k * N + n0 + tx];
    }
    __syncthreads();
    #pragma unroll
    for (int i = ty; i < 32; i += 8) {
        const int n = n0 + i;
        if (n < N && k0 + tx < K) Wt[(size_t)n * K + k0 + tx] = (f16)t[tx][i];
    }
}

// f32 -> f16 elementwise (n % 4 == 0); also initializes deg[0..N_NODES)=1.
__global__ void f2h_kernel(const float* __restrict__ in, f16* __restrict__ out, int n,
                           float* __restrict__ deg)
{
    const int gid = blockIdx.x * 256 + threadIdx.x;
    if (gid < N_NODES) deg[gid] = 1.0f;   // self-loop weight
    const int i = gid * 4;
    if (i < n) {
        const float4 v = *(const float4*)(in + i);
        out[i + 0] = (f16)v.x; out[i + 1] = (f16)v.y;
        out[i + 2] = (f16)v.z; out[i + 3] = (f16)v.w;
    }
}

// ---------------------------------------------------------------------------
// Fused conv + kv-sum + q materialization (unchanged).
// ---------------------------------------------------------------------------
#define KV_CHUNK 32
#define KV_BLOCKS (N_NODES / KV_CHUNK)   // 625
__global__ __launch_bounds__(256, 2)
void kv_fused_kernel(const f16* __restrict__ qkv, const float* __restrict__ cw,
                     f16* __restrict__ q_all, float* __restrict__ kvg,
                     float* __restrict__ kv_part)
{
    __shared__ f16 rows[5][TD];
    const int tid = threadIdx.x;
    const int n0 = blockIdx.x * KV_CHUNK;
    const int h = tid >> 1, d0 = (tid & 1) * 4;

    float wk[4][5], wv[8][5], wq[8][5];
    if (h >= 64) {
        const int cb = (h - 64) * 24;
        #pragma unroll
        for (int dd = 0; dd < 4; ++dd)
            #pragma unroll
            for (int t = 0; t < 5; ++t)
                wk[dd][t] = cw[(cb + 8 + d0 + dd) * 5 + t];
        #pragma unroll
        for (int e = 0; e < 8; ++e)
            #pragma unroll
            for (int t = 0; t < 5; ++t)
                wv[e][t] = cw[(cb + 16 + e) * 5 + t];
    }
    if (tid >= 64 && tid < 128) {
        const int cb = (tid - 64) * 24;
        #pragma unroll
        for (int d = 0; d < 8; ++d)
            #pragma unroll
            for (int t = 0; t < 5; ++t)
                wq[d][t] = cw[(cb + d) * 5 + t];
    }

    for (int r = n0 - 2; r <= n0 + 2; ++r) {
        const int slot = ((r % 5) + 5) % 5;
        if (tid < 192) {
            f16x8 v = {0, 0, 0, 0, 0, 0, 0, 0};
            if (r >= 0 && r < N_NODES)
                v = *(const f16x8*)(qkv + (size_t)r * TD + tid * 8);
            *(f16x8*)(&rows[slot][tid * 8]) = v;
        }
    }
    __syncthreads();

    float acc[36] = {};

    for (int i = 0; i < KV_CHUNK; ++i) {
        const int n = n0 + i;

        f16x8 pre = {0, 0, 0, 0, 0, 0, 0, 0};
        const bool doPre = (i < KV_CHUNK - 1) && (tid < 192);
        if (doPre && (n + 3) < N_NODES)
            pre = *(const f16x8*)(qkv + (size_t)(n + 3) * TD + tid * 8);

        const f16* wr[5] = { rows[(((n - 2) % 5) + 5) % 5],
                             rows[(((n - 1) % 5) + 5) % 5],
                             rows[n % 5],
                             rows[(n + 1) % 5],
                             rows[(n + 2) % 5] };

        float kv4[4], vv[8];
        if (h < 64) {
            const int cb = h * 24;
            const f16x4 kd = *(const f16x4*)(wr[2] + cb + 8 + d0);
            const f16x8 vd = *(const f16x8*)(wr[2] + cb + 16);
            #pragma unroll
            for (int dd = 0; dd < 4; ++dd) kv4[dd] = fmaxf((float)kd[dd], 0.f);
            #pragma unroll
            for (int e = 0; e < 8; ++e) vv[e] = (float)vd[e];
        } else {
            const int cb = (h - 64) * 24;
            f16x4 ka[5]; f16x8 va[5];
            #pragma unroll
            for (int t = 0; t < 5; ++t) {
                ka[t] = *(const f16x4*)(wr[t] + cb + 8 + d0);
                va[t] = *(const f16x8*)(wr[t] + cb + 16);
            }
            #pragma unroll
            for (int dd = 0; dd < 4; ++dd) {
                float s = 0.f;
                #pragma unroll
                for (int t = 0; t < 5; ++t) s = fmaf(wk[dd][t], (float)ka[t][dd], s);
                kv4[dd] = fmaxf(s, 0.f);
            }
            #pragma unroll
            for (int e = 0; e < 8; ++e) {
                float s = 0.f;
                #pragma unroll
                for (int t = 0; t < 5; ++t) s = fmaf(wv[e][t], (float)va[t][e], s);
                vv[e] = s;
            }
        }
        #pragma unroll
        for (int dd = 0; dd < 4; ++dd) {
            #pragma unroll
            for (int e = 0; e < 8; ++e)
                acc[dd * 9 + e] = fmaf(kv4[dd], vv[e], acc[dd * 9 + e]);
            acc[dd * 9 + 8] += kv4[dd];
        }

        if (tid < 128) {
            f16x8 qv;
            if (tid < 64) {
                qv = *(const f16x8*)(wr[2] + tid * 24);
                #pragma unroll
                for (int d = 0; d < 8; ++d)
                    qv[d] = qv[d] > (f16)0 ? qv[d] : (f16)0;
            } else {
                const int cb = (tid - 64) * 24;
                f16x8 qa[5];
                #pragma unroll
                for (int t = 0; t < 5; ++t) qa[t] = *(const f16x8*)(wr[t] + cb);
                #pragma unroll
                for (int d = 0; d < 8; ++d) {
                    float s = 0.f;
                    #pragma unroll
                    for (int t = 0; t < 5; ++t) s = fmaf(wq[d][t], (float)qa[t][d], s);
                    qv[d] = (f16)fmaxf(s, 0.f);
                }
            }
            *(f16x8*)(q_all + (size_t)n * 1024 + tid * 8) = qv;
        }

        __syncthreads();
        if (doPre)
            *(f16x8*)(&rows[(n + 3) % 5][tid * 8]) = pre;
        __syncthreads();
    }

    if (kv_part) {
        float* dst = kv_part + (size_t)blockIdx.x * 9216 + tid * 36;
        #pragma unroll
        for (int i = 0; i < 36; ++i) dst[i] = acc[i];
    } else {
        #pragma unroll
        for (int dd = 0; dd < 4; ++dd)
            #pragma unroll
            for (int e = 0; e < 9; ++e)
                atomicAdd(&kvg[h * 72 + (d0 + dd) * 9 + e], acc[dd * 9 + e]);
    }
}

// kvg[j] = sum_b kv_part[b][j], j in [0,9216). Grid: 36 x 256.
__global__ void kv_reduce_kernel(const float* __restrict__ kv_part,
                                 float* __restrict__ kvg)
{
    const int j = blockIdx.x * 256 + threadIdx.x;
    float s = 0.f;
    for (int b = 0; b < KV_BLOCKS; ++b)
        s += kv_part[(size_t)b * 9216 + j];
    kvg[j] = s;
}

// ---------------------------------------------------------------------------
// o[n, h*8+e] = (sum_d q*kv[h,d,e]) / (sum_d q*kv[h,d,8] + 1e-15)
// ---------------------------------------------------------------------------
__global__ __launch_bounds__(256)
void attn_o_kernel(const f16* __restrict__ q_all, const float* __restrict__ kvg,
                   f16* __restrict__ o)
{
    __shared__ float kvt[72][128];   // [d*9+e][h]
    const int tid = threadIdx.x;
    for (int i = tid; i < 9216; i += 256) {
        const int hh = i & 127, j = i >> 7;
        kvt[j][hh] = kvg[hh * 72 + j];
    }
    __syncthreads();
    const int h = tid & 127, sub = tid >> 7;
    for (int nb = blockIdx.x; nb < N_NODES / 2; nb += gridDim.x) {
        const int n = nb * 2 + sub;
        const f16x8 qv8 = *(const f16x8*)(q_all + (size_t)n * 1024 + h * 8);
        float q[8];
        #pragma unroll
        for (int d = 0; d < 8; ++d) q[d] = (float)qv8[d];
        float num[8], den = 0.f;
        #pragma unroll
        for (int e = 0; e < 8; ++e) {
            float s = 0.f;
            #pragma unroll
            for (int d = 0; d < 8; ++d) s = fmaf(q[d], kvt[d * 9 + e][h], s);
            num[e] = s;
        }
        #pragma unroll
        for (int d = 0; d < 8; ++d) den = fmaf(q[d], kvt[d * 9 + 8][h], den);
        const float rinv = 1.f / (den + 1e-15f);
        f16x8 ov;
        #pragma unroll
        for (int e = 0; e < 8; ++e) ov[e] = (f16)(num[e] * rinv);
        *(f16x8*)(o + (size_t)n * 1024 + h * 8) = ov;
    }
}

// ---------------------------------------------------------------------------
// out_h = f16(resid + LN(y)*g + b). resid f16. out_h may alias y.
// ---------------------------------------------------------------------------
__global__ void ln_res_kernel(const f16* __restrict__ y, const f16* __restrict__ resid,
                              const float* __restrict__ g, const float* __restrict__ b,
                              f16* __restrict__ out_h)
{
    const int row = blockIdx.x;
    const int tid = threadIdx.x;
    const f16* yr = y + (size_t)row * DMODEL;
    const float v0 = (float)yr[tid], v1 = (float)yr[tid + 256];
    __shared__ float red[4], red2[4];
    float s = v0 + v1;
    #pragma unroll
    for (int o = 32; o > 0; o >>= 1) s += __shfl_down(s, o);
    if ((tid & 63) == 0) red[tid >> 6] = s;
    __syncthreads();
    const float mean = (red[0] + red[1] + red[2] + red[3]) * (1.0f / DMODEL);
    const float d0 = v0 - mean, d1 = v1 - mean;
    float q = d0 * d0 + d1 * d1;
    #pragma unroll
    for (int o = 32; o > 0; o >>= 1) q += __shfl_down(q, o);
    if ((tid & 63) == 0) red2[tid >> 6] = q;
    __syncthreads();
    const float var = (red2[0] + red2[1] + red2[2] + red2[3]) * (1.0f / DMODEL);
    const float inv = rsqrtf(var + 1e-5f);
    const f16* rr = resid + (size_t)row * DMODEL;
    const float o0 = (float)rr[tid]       + d0 * inv * g[tid]       + b[tid];
    const float o1 = (float)rr[tid + 256] + d1 * inv * g[tid + 256] + b[tid + 256];
    f16* oh = out_h + (size_t)row * DMODEL;
    oh[tid] = (f16)o0;
    oh[tid + 256] = (f16)o1;
}

// ---------------------------------------------------------------------------
// Graph prep (fused): one edge pass does deg-accum + count.
// ---------------------------------------------------------------------------
__global__ void edge_prep_kernel(const int* __restrict__ eirow, const float* __restrict__ ea,
                                 float* __restrict__ deg, int* __restrict__ cnt)
{
    const int e = blockIdx.x * 256 + threadIdx.x;
    if (e < N_EDGES) {
        const int r = eirow[e];
        atomicAdd(&deg[r], ea[e]);
        atomicAdd(&cnt[r], 1);
    }
}

// Single-block scan of cnt -> rowstart/cursor; also dis = rsqrt(deg) (fused).
__global__ void scan_kernel(const int* __restrict__ cnt, int* __restrict__ rowstart,
                            int* __restrict__ cursor, const float* __restrict__ deg,
                            float* __restrict__ dis)
{
    __shared__ int ls[1024];
    const int tid = threadIdx.x;
    const int base = tid * 20;
    int local[20];
    int s = 0;
    #pragma unroll
    for (int i = 0; i < 20; ++i) {
        const int idx = base + i;
        const int v = (idx < N_NODES) ? cnt[idx] : 0;
        local[i] = s;
        s += v;
        if (idx < N_NODES) dis[idx] = rsqrtf(deg[idx]);   // deg >= 1 always
    }
    ls[tid] = s;
    __syncthreads();
    for (int off = 1; off < 1024; off <<= 1) {
        const int v = (tid >= off) ? ls[tid - off] : 0;
        __syncthreads();
        ls[tid] += v;
        __syncthreads();
    }
    const int excl = (tid == 0) ? 0 : ls[tid - 1];
    #pragma unroll
    for (int i = 0; i < 20; ++i) {
        const int idx = base + i;
        if (idx < N_NODES) {
            const int st = excl + local[i];
            rowstart[idx] = st;
            cursor[idx] = st;
        }
    }
    if (tid == 1023) rowstart[N_NODES] = ls[1023];
}

__global__ void scatter_kernel(const int* __restrict__ eirow, int* __restrict__ cursor,
                               int* __restrict__ sorted)
{
    const int e = blockIdx.x * 256 + threadIdx.x;
    if (e < N_EDGES) {
        const int r = eirow[e];
        const int p = atomicAdd(&cursor[r], 1);
        sorted[p] = e;
    }
}

// ---------------------------------------------------------------------------
// Aggregation v3 (unchanged): LDS metadata prefetch + 4-wave row gathers.
// ---------------------------------------------------------------------------
__global__ __launch_bounds__(256)
void agg_kernel(const f16* __restrict__ srcf_h, const int* __restrict__ eicol,
                const float* __restrict__ ea, const float* __restrict__ dis,
                const int* __restrict__ rowstart, const int* __restrict__ sorted,
                f16* __restrict__ agg)
{
    __shared__ int   cbuf[256];
    __shared__ float wbuf[256];
    __shared__ float part[4][512];
    const int i = blockIdx.x;
    const int tid = threadIdx.x;
    const int lane = tid & 63, wv = tid >> 6;
    const float di = dis[i];
    const int s = rowstart[i];
    const int deg = rowstart[i + 1] - s;

    float acc[8] = {};
    for (int base = 0; base < deg; base += 256) {
        const int m = min(256, deg - base);
        if (tid < m) {
            const int e = sorted[s + base + tid];
            const int c = eicol[e];
            cbuf[tid] = c;
            wbuf[tid] = di * ea[e] * dis[c];
        }
        __syncthreads();
        #pragma unroll 2
        for (int p = wv; p < m; p += 4) {
            const int c = cbuf[p];
            const float w = wbuf[p];
            const f16x8 v = *(const f16x8*)(srcf_h + (size_t)c * DMODEL + lane * 8);
            #pragma unroll
            for (int j = 0; j < 8; ++j) acc[j] = fmaf(w, (float)v[j], acc[j]);
        }
        __syncthreads();
    }
    #pragma unroll
    for (int j = 0; j < 8; ++j) part[wv][lane * 8 + j] = acc[j];
    __syncthreads();
    const float wself = di * di;
    const f16x2 vs = *(const f16x2*)(srcf_h + (size_t)i * DMODEL + tid * 2);
    float a0 = wself * (float)vs[0], a1 = wself * (float)vs[1];
    #pragma unroll
    for (int w = 0; w < 4; ++w) {
        a0 += part[w][tid * 2];
        a1 += part[w][tid * 2 + 1];
    }
    f16x2 o;
    o[0] = (f16)fmaxf(a0, 0.f);
    o[1] = (f16)fmaxf(a1, 0.f);
    *(f16x2*)(agg + (size_t)i * DMODEL + tid * 2) = o;
}

// ---------------------------------------------------------------------------
// Workspace layout (bytes) — unchanged from rounds 12-19.
// ---------------------------------------------------------------------------
static constexpr size_t OFF_HH    = 0;              // f16 20,480,000
static constexpr size_t OFF_FF    = 20480000ull;    // f16 20,480,000
static constexpr size_t OFF_QKV   = 40960000ull;    // f16 61,440,000
static constexpr size_t OFF_SRC2  = 40960000ull;    // f16 20,480,000 (alias)
static constexpr size_t OFF_FFH   = 61440000ull;    // f16 81,920,000 (alias)
static constexpr size_t OFF_AGG   = 61440000ull;    // f16 40,960,000 (alias)
static constexpr size_t OFF_XH    = 102400000ull;   // f16 10,240,000
static constexpr size_t OFF_ATTN  = 102400000ull;   // f16 40,960,000 (alias)
static constexpr size_t WT_IN     = 143360000ull;
static constexpr size_t WT_QKV    = 143622144ull;
static constexpr size_t WT_PROJ   = 145195008ull;
static constexpr size_t WT_W1     = 146243584ull;
static constexpr size_t WT_W2     = 148340736ull;
static constexpr size_t WT_OUT    = 150437888ull;
static constexpr size_t OFF_KV    = 150568960ull;
static constexpr size_t OFF_DEG   = 150605824ull;
static constexpr size_t OFF_DIS   = 150685824ull;
static constexpr size_t OFF_RS    = 150765824ull;
static constexpr size_t OFF_CUR   = 150845888ull;
static constexpr size_t OFF_CNT   = 150925888ull;
static constexpr size_t OFF_SORT  = 151005888ull;   // -> 152,285,888
static constexpr size_t OFF_KVP   = 152285888ull;   // -> 175,325,888
static constexpr size_t WS_NEED_KVP = 175325888ull;

extern "C" void kernel_launch(void* const* d_in, const int* in_sizes, int n_in,
                              void* d_out, int out_size, void* d_ws, size_t ws_size,
                              hipStream_t stream)
{
    const float* x      = (const float*)d_in[0];
    const int*   ei     = (const int*)d_in[1];
    const float* ea     = (const float*)d_in[2];
    const float* pe     = (const float*)d_in[4];
    const float* W_in   = (const float*)d_in[5];
    const float* b_in   = (const float*)d_in[6];
    const float* W_qkv  = (const float*)d_in[7];
    const float* conv_w = (const float*)d_in[8];
    const float* W_proj = (const float*)d_in[9];
    const float* b_proj = (const float*)d_in[10];
    const float* g1     = (const float*)d_in[11];
    const float* beta1  = (const float*)d_in[12];
    const float* W1     = (const float*)d_in[13];
    const float* bf1    = (const float*)d_in[14];
    const float* W2     = (const float*)d_in[15];
    const float* bf2    = (const float*)d_in[16];
    const float* g2     = (const float*)d_in[17];
    const float* beta2  = (const float*)d_in[18];
    const float* W_out  = (const float*)d_in[19];
    const float* b_out  = (const float*)d_in[20];

    char* ws = (char*)d_ws;
    f16*   h_h    = (f16*)(ws + OFF_HH);
    f16*   ff     = (f16*)(ws + OFF_FF);
    f16*   qkv    = (f16*)(ws + OFF_QKV);
    f16*   src2   = (f16*)(ws + OFF_SRC2);
    f16*   ffh    = (f16*)(ws + OFF_FFH);
    f16*   agg    = (f16*)(ws + OFF_AGG);
    f16*   x_h    = (f16*)(ws + OFF_XH);
    f16*   q_all  = (f16*)(ws + OFF_ATTN);
    f16*   wt_in   = (f16*)(ws + WT_IN);
    f16*   wt_qkv  = (f16*)(ws + WT_QKV);
    f16*   wt_proj = (f16*)(ws + WT_PROJ);
    f16*   wt_w1   = (f16*)(ws + WT_W1);
    f16*   wt_w2   = (f16*)(ws + WT_W2);
    f16*   wt_out  = (f16*)(ws + WT_OUT);
    float* kvg    = (float*)(ws + OFF_KV);
    float* deg    = (float*)(ws + OFF_DEG);
    float* dis    = (float*)(ws + OFF_DIS);
    int*   rs     = (int*)(ws + OFF_RS);
    int*   cur    = (int*)(ws + OFF_CUR);
    int*   cnt    = (int*)(ws + OFF_CNT);
    int*   sorted = (int*)(ws + OFF_SORT);
    float* outp   = (float*)d_out;

    const bool twoStage = (ws_size >= WS_NEED_KVP);
    float* kv_part = twoStage ? (float*)(ws + OFF_KVP) : nullptr;

    const int* eirow = ei;
    const int* eicol = ei + N_EDGES;

    if (!twoStage)
        hipMemsetAsync(kvg, 0, 9216 * sizeof(float), stream);
    hipMemsetAsync(cnt, 0, N_NODES * sizeof(int), stream);

    // 0. weight transpose+convert (f32 [K][N] -> f16 [N][K])
    wt_kernel<<<dim3(DIN / 32,   DMODEL / 32), 256, 0, stream>>>(W_in,   wt_in,   DIN,    DMODEL);
    wt_kernel<<<dim3(DMODEL / 32, TD / 32),    256, 0, stream>>>(W_qkv,  wt_qkv,  DMODEL, TD);
    wt_kernel<<<dim3(1024 / 32,  DMODEL / 32), 256, 0, stream>>>(W_proj, wt_proj, 1024,   DMODEL);
    wt_kernel<<<dim3(DMODEL / 32, FFD / 32),   256, 0, stream>>>(W1,     wt_w1,   DMODEL, FFD);
    wt_kernel<<<dim3(FFD / 32,   DMODEL / 32), 256, 0, stream>>>(W2,     wt_w2,   FFD,    DMODEL);
    wt_kernel<<<dim3(DMODEL / 32, DOUT / 32),  256, 0, stream>>>(W_out,  wt_out,  DMODEL, DOUT);
    // 0b. x -> f16 (+ deg init fused)
    f2h_kernel<<<(N_NODES * DIN) / 1024, 256, 0, stream>>>(x, x_h, N_NODES * DIN, deg);

    const int MT = (N_NODES + 127) / 128;   // 157

    // 1. h_h = f16(x@W_in + b_in + pe)
    gemm_mfma<f16, 1, 1, 0><<<MT * (DMODEL / 128), 256, 0, stream>>>(
        x_h, wt_in, b_in, pe, h_h, N_NODES, DMODEL, DIN);
    // 2. qkv = h_h@W_qkv (f16)
    gemm_mfma<f16, 0, 0, 0><<<MT * (TD / 128), 256, 0, stream>>>(
        h_h, wt_qkv, nullptr, nullptr, qkv, N_NODES, TD, DMODEL);
    // 3. fused conv + kv partials + q materialization
    kv_fused_kernel<<<KV_BLOCKS, 256, 0, stream>>>(qkv, conv_w, q_all, kvg, kv_part);
    if (twoStage)
        kv_reduce_kernel<<<36, 256, 0, stream>>>(kv_part, kvg);
    // 4. attention readout (in-place over q_all)
    attn_o_kernel<<<2500, 256, 0, stream>>>(q_all, kvg, q_all);
    // 5. src2 = attn_o@W_proj + b_proj (f16)
    gemm_mfma<f16, 1, 0, 0><<<MT * (DMODEL / 128), 256, 0, stream>>>(
        q_all, wt_proj, b_proj, nullptr, src2, N_NODES, DMODEL, 1024);
    // 6. src2 = f16(h_h + LN(src2))  (in-place)
    ln_res_kernel<<<N_NODES, 256, 0, stream>>>(src2, h_h, g1, beta1, src2);
    // 7. ffh = relu(src2@W1 + bf1) (f16)
    gemm_mfma<f16, 1, 0, 1><<<MT * (FFD / 128), 256, 0, stream>>>(
        src2, wt_w1, bf1, nullptr, ffh, N_NODES, FFD, DMODEL);
    // 8. ff = ffh@W2 + bf2 (f16)
    gemm_mfma<f16, 1, 0, 0><<<MT * (DMODEL / 128), 256, 0, stream>>>(
        ffh, wt_w2, bf2, nullptr, ff, N_NODES, DMODEL, FFD);
    // 9. ff = f16(src2 + LN(ff))  (in-place; agg gather source)
    ln_res_kernel<<<N_NODES, 256, 0, stream>>>(ff, src2, g2, beta2, ff);
    // 10. fused edge pass: deg accumulation + per-row count
    edge_prep_kernel<<<(N_EDGES + 255) / 256, 256, 0, stream>>>(eirow, ea, deg, cnt);
    // 11. scan (+ dis fused) and scatter (counting sort by destination row)
    scan_kernel<<<1, 1024, 0, stream>>>(cnt, rs, cur, deg, dis);
    scatter_kernel<<<(N_EDGES + 255) / 256, 256, 0, stream>>>(eirow, cur, sorted);
    // 12. aggregation
    agg_kernel<<<N_NODES, 256, 0, stream>>>(ff, eicol, ea, dis, rs, sorted, agg);
    // 13. out = relu(agg)@W_out + b_out (f32)
    gemm_mfma<float, 1, 0, 0><<<MT * (DOUT / 128), 256, 0, stream>>>(
        agg, wt_out, b_out, nullptr, outp, N_NODES, DOUT, DMODEL);
}